// Round 1
// baseline (16146.568 us; speedup 1.0000x reference)
//
#include <hip/hip_runtime.h>

#define BATCH 8192
#define N 64
#define HID 512
#define D 192          // 3*N
#define JPB 16         // j's per block
#define NT 512         // threads per block

__global__ __launch_bounds__(NT, 2)
void hnn_hess_kernel(const float* __restrict__ x, const float* __restrict__ q,
                     const float* __restrict__ p, const float* __restrict__ W1,
                     const float* __restrict__ b1, const float* __restrict__ W2,
                     const float* __restrict__ b2, const float* __restrict__ W3,
                     float* __restrict__ out)
{
    __shared__ float zs[D];
    __shared__ float h1s[HID], t1s[HID], v2s[HID], cs[HID], ss[HID];
    __shared__ float awf[JPB][HID];   // holds aw (=W1_xj * t1), then reused for F (=E*c)
    __shared__ float red[8][2*JPB];

    const int tid = threadIdx.x;
    const int bid = blockIdx.x;
    const int b  = bid >> 2;          // sample
    const int jg = bid & 3;           // j-group
    const int j0 = jg * JPB;

    // ---- load z = concat(x[b], q[b], p[b]) ----
    if (tid < D) {
        float v;
        if (tid < N)        v = x[b*N + tid];
        else if (tid < 2*N) v = q[b*N + tid - N];
        else                v = p[b*N + tid - 2*N];
        zs[tid] = v;
    }
    __syncthreads();

    // ---- layer 1: a1 = z@W1 + b1 (thread = hidden unit) ----
    float acc = b1[tid];
    #pragma unroll 4
    for (int k = 0; k < D; ++k)
        acc += zs[k] * W1[k*HID + tid];
    const float h1 = tanhf(acc);
    const float t1 = 1.0f - h1*h1;
    h1s[tid] = h1;
    t1s[tid] = t1;
    __syncthreads();

    // ---- layer 2: a2 = h1@W2 + b2 (thread = m) ----
    acc = b2[tid];
    {
        const float4* h14 = reinterpret_cast<const float4*>(h1s);
        for (int k4 = 0; k4 < HID/4; ++k4) {
            float4 h = h14[k4];
            acc += h.x * W2[(4*k4+0)*HID + tid];
            acc += h.y * W2[(4*k4+1)*HID + tid];
            acc += h.z * W2[(4*k4+2)*HID + tid];
            acc += h.w * W2[(4*k4+3)*HID + tid];
        }
    }
    const float h2 = tanhf(acc);
    const float t2 = 1.0f - h2*h2;
    const float v2 = W3[tid] * t2;
    v2s[tid] = v2;
    cs[tid]  = -2.0f * h2 * v2;
    __syncthreads();

    // ---- u[k] = W2[k,:].v2 ; s[k] = -2 h1 t1 u (thread = k, own-row stream) ----
    const float4* w2row = reinterpret_cast<const float4*>(W2 + (size_t)tid * HID);
    {
        float uacc = 0.f;
        const float4* v24 = reinterpret_cast<const float4*>(v2s);
        #pragma unroll 4
        for (int m4 = 0; m4 < HID/4; ++m4) {
            float4 w = w2row[m4];
            float4 v = v24[m4];
            uacc += w.x*v.x + w.y*v.y + w.z*v.z + w.w*v.w;
        }
        ss[tid] = -2.0f * h1 * t1 * uacc;
    }

    // ---- aw[j][k] = W1[x_j, k] * t1[k]  (thread = k) ----
    for (int j = 0; j < JPB; ++j)
        awf[j][tid] = W1[(j0 + j)*HID + tid] * t1;
    __syncthreads();

    // ---- E[j][m] = sum_k aw[j][k] * W2[k,m]   (thread = m) ----
    float e[JPB];
    #pragma unroll
    for (int j = 0; j < JPB; ++j) e[j] = 0.f;
    for (int k4 = 0; k4 < HID/4; ++k4) {
        const float w0 = W2[(4*k4+0)*HID + tid];
        const float w1 = W2[(4*k4+1)*HID + tid];
        const float w2v = W2[(4*k4+2)*HID + tid];
        const float w3v = W2[(4*k4+3)*HID + tid];
        #pragma unroll
        for (int j = 0; j < JPB; ++j) {
            const float4 a = reinterpret_cast<const float4*>(awf[j])[k4];
            e[j] += a.x*w0 + a.y*w1 + a.z*w2v + a.w*w3v;
        }
    }
    __syncthreads();   // all reads of aw done
    {
        const float cm = cs[tid];
        #pragma unroll
        for (int j = 0; j < JPB; ++j)
            awf[j][tid] = e[j] * cm;   // F[j][m]
    }
    __syncthreads();

    // ---- R[j][k] = sum_m F[j][m] * W2[k,m]  (thread = k, own-row stream) ----
    float r[JPB];
    #pragma unroll
    for (int j = 0; j < JPB; ++j) r[j] = 0.f;
    for (int m4 = 0; m4 < HID/4; ++m4) {
        const float4 w = w2row[m4];
        #pragma unroll
        for (int j = 0; j < JPB; ++j) {
            const float4 f = reinterpret_cast<const float4*>(awf[j])[m4];
            r[j] += f.x*w.x + f.y*w.y + f.z*w.z + f.w*w.w;
        }
    }

    // ---- fold second term + per-thread partials ----
    const float sk = ss[tid];
    float vq[JPB], vp[JPB];
    #pragma unroll
    for (int j = 0; j < JPB; ++j) {
        const int jj = j0 + j;
        const float w1x = W1[jj*HID + tid];
        const float w1q = W1[(N  + jj)*HID + tid];
        const float w1p = W1[(2*N + jj)*HID + tid];
        const float base = r[j]*t1 + sk*w1x;   // R[j,k]*t1[k] + s[k]*W1[xj,k]
        vq[j] = w1q * base;                    // -> dH_dq_dx[j] partial
        vp[j] = w1p * base;                    // -> dH_dp_dx[j] partial
    }

    // ---- reduce 2*JPB sums over 512 threads ----
    const int lane = tid & 63;
    const int wv   = tid >> 6;
    #pragma unroll
    for (int j = 0; j < JPB; ++j) {
        float v = vq[j];
        for (int off = 32; off; off >>= 1) v += __shfl_down(v, off, 64);
        if (lane == 0) red[wv][j] = v;
        float u = vp[j];
        for (int off = 32; off; off >>= 1) u += __shfl_down(u, off, 64);
        if (lane == 0) red[wv][JPB + j] = u;
    }
    __syncthreads();

    if (tid < 2*JPB) {
        float v = 0.f;
        #pragma unroll
        for (int w = 0; w < 8; ++w) v += red[w][tid];
        if (tid < JPB) {
            // dH_dq_dx -> output 1 (p_dot_hat = -dH_dq_dx)
            out[(size_t)BATCH*N + (size_t)b*N + j0 + tid] = -v;
        } else {
            // dH_dp_dx -> output 0 (q_dot_hat = -dH_dp_dx)
            out[(size_t)b*N + j0 + (tid - JPB)] = -v;
        }
    }
}

extern "C" void kernel_launch(void* const* d_in, const int* in_sizes, int n_in,
                              void* d_out, int out_size, void* d_ws, size_t ws_size,
                              hipStream_t stream) {
    const float* x  = (const float*)d_in[0];
    const float* q  = (const float*)d_in[1];
    const float* p  = (const float*)d_in[2];
    const float* W1 = (const float*)d_in[3];
    const float* b1 = (const float*)d_in[4];
    const float* W2 = (const float*)d_in[5];
    const float* b2 = (const float*)d_in[6];
    const float* W3 = (const float*)d_in[7];
    // b3 (d_in[8]) does not affect any derivative
    float* out = (float*)d_out;

    hnn_hess_kernel<<<BATCH * 4, NT, 0, stream>>>(x, q, p, W1, b1, W2, b2, W3, out);
}

// Round 2
// 2412.502 us; speedup vs baseline: 6.6929x; 6.6929x over previous
//
#include <hip/hip_runtime.h>

#define BATCH 8192
#define NQ 64          // spatial dim n
#define HID 512
#define DIN 192        // 3*n
#define NT 512         // threads per block (8 waves)

typedef _Float16 f16;
typedef _Float16 f16x8 __attribute__((ext_vector_type(8)));
typedef float f32x4 __attribute__((ext_vector_type(4)));

// W2 in f16, two layouts (device globals; rewritten every launch by prep_w2)
__device__ f16 g_w2f[HID * HID];   // [k][m]  (rows = hidden1 k, cols = hidden2 m)
__device__ f16 g_w2t[HID * HID];   // [m][k]  (transposed)

__global__ void prep_w2(const float* __restrict__ W2) {
    const int k = blockIdx.x;      // 512 blocks
    const int m = threadIdx.x;     // 512 threads
    const float v = W2[k * HID + m];
    g_w2f[k * HID + m] = (f16)v;
    g_w2t[m * HID + k] = (f16)v;
}

__global__ __launch_bounds__(NT)
void hnn_mfma(const float* __restrict__ x, const float* __restrict__ q,
              const float* __restrict__ p, const float* __restrict__ W1,
              const float* __restrict__ b1, const float* __restrict__ b2,
              const float* __restrict__ W3, float* __restrict__ out)
{
    __shared__ float zs[DIN];
    __shared__ float h1s[HID], t1s[HID], v2s[HID], cs[HID], ss[HID];
    __shared__ f16 awF[NQ * HID];          // 64KB: holds aw (=W1_x * t1), then F (=E*c)
    __shared__ float red[NQ][2];

    const int tid  = threadIdx.x;
    const int lane = tid & 63;
    const int wv   = tid >> 6;             // wave id 0..7
    const int b    = blockIdx.x;

    // ---- stage 0: load z, zero reduction buffer ----
    if (tid < DIN) {
        float v;
        if (tid < NQ)          v = x[b * NQ + tid];
        else if (tid < 2 * NQ) v = q[b * NQ + tid - NQ];
        else                   v = p[b * NQ + tid - 2 * NQ];
        zs[tid] = v;
    }
    if (tid < 2 * NQ) ((float*)red)[tid] = 0.f;
    __syncthreads();

    // ---- layer 1: thread = hidden1 unit ----
    float acc = b1[tid];
    #pragma unroll 4
    for (int k = 0; k < DIN; ++k) acc += zs[k] * W1[k * HID + tid];
    const float h1 = tanhf(acc);
    const float t1 = 1.f - h1 * h1;
    h1s[tid] = h1;
    t1s[tid] = t1;
    __syncthreads();

    // ---- layer 2 (f16 weights): thread = hidden2 unit m ----
    acc = b2[tid];
    {
        const float4* h14 = (const float4*)h1s;
        for (int k4 = 0; k4 < HID / 4; ++k4) {
            float4 h = h14[k4];
            acc += h.x * (float)g_w2f[(4 * k4 + 0) * HID + tid];
            acc += h.y * (float)g_w2f[(4 * k4 + 1) * HID + tid];
            acc += h.z * (float)g_w2f[(4 * k4 + 2) * HID + tid];
            acc += h.w * (float)g_w2f[(4 * k4 + 3) * HID + tid];
        }
    }
    const float h2 = tanhf(acc);
    const float t2 = 1.f - h2 * h2;
    const float v2 = W3[tid] * t2;
    v2s[tid] = v2;
    cs[tid]  = -2.f * h2 * v2;
    __syncthreads();

    // ---- u[k] = W2[k,:].v2 ; s[k] = -2 h1 t1 u  (thread = k, own f16 row) ----
    {
        const f16x8* w2row8 = (const f16x8*)(g_w2f + (size_t)tid * HID);
        const float4* v24 = (const float4*)v2s;
        float uacc = 0.f;
        for (int m8 = 0; m8 < HID / 8; ++m8) {
            f16x8 w = w2row8[m8];
            float4 va = v24[2 * m8], vb = v24[2 * m8 + 1];
            uacc += (float)w[0] * va.x + (float)w[1] * va.y + (float)w[2] * va.z + (float)w[3] * va.w;
            uacc += (float)w[4] * vb.x + (float)w[5] * vb.y + (float)w[6] * vb.z + (float)w[7] * vb.w;
        }
        ss[tid] = -2.f * h1 * t1 * uacc;
    }

    // ---- build aw[j][k] = W1[x_j, k] * t1[k] in f16, XOR-swizzled 16B chunks ----
    // thread: row j = tid&63, chunk-group cg = tid>>6 (t1s reads broadcast across wave)
    {
        const int j  = tid & 63;
        const int cg = tid >> 6;
        const float* w1row = W1 + (size_t)j * HID;   // x-rows are rows 0..63 of W1
        f16x8* aw8 = (f16x8*)awF;
        #pragma unroll
        for (int c = 0; c < 8; ++c) {
            const int kc   = cg * 8 + c;             // chunk index 0..63
            const int col0 = kc * 8;
            float4 wa = *(const float4*)(w1row + col0);
            float4 wb = *(const float4*)(w1row + col0 + 4);
            float4 ta = *(const float4*)(t1s + col0);
            float4 tb = *(const float4*)(t1s + col0 + 4);
            f16x8 h;
            h[0] = (f16)(wa.x * ta.x); h[1] = (f16)(wa.y * ta.y);
            h[2] = (f16)(wa.z * ta.z); h[3] = (f16)(wa.w * ta.w);
            h[4] = (f16)(wb.x * tb.x); h[5] = (f16)(wb.y * tb.y);
            h[6] = (f16)(wb.z * tb.z); h[7] = (f16)(wb.w * tb.w);
            aw8[j * 64 + (kc ^ (j & 7))] = h;
        }
    }
    __syncthreads();

    // ---- E GEMM: E[64 j][512 m] = aw @ W2, wave owns m-tiles [wv*64, wv*64+64) ----
    const int n0 = wv * 64;
    f32x4 acc4[4][4];   // [jt][nt]
    #pragma unroll
    for (int a = 0; a < 4; ++a)
        #pragma unroll
        for (int c = 0; c < 4; ++c) acc4[a][c] = (f32x4){0.f, 0.f, 0.f, 0.f};

    const f16x8* awF8 = (const f16x8*)awF;
    {
        const f16* bptr = g_w2t + (size_t)(n0 + (lane & 15)) * HID + 8 * (lane >> 4);
        #pragma unroll 2
        for (int ks = 0; ks < 16; ++ks) {
            f16x8 afr[4], bfr[4];
            #pragma unroll
            for (int jt = 0; jt < 4; ++jt) {
                const int row = jt * 16 + (lane & 15);
                afr[jt] = awF8[row * 64 + ((ks * 4 + (lane >> 4)) ^ (row & 7))];
            }
            #pragma unroll
            for (int nt = 0; nt < 4; ++nt)
                bfr[nt] = *(const f16x8*)(bptr + nt * 16 * HID + ks * 32);
            #pragma unroll
            for (int jt = 0; jt < 4; ++jt)
                #pragma unroll
                for (int nt = 0; nt < 4; ++nt)
                    acc4[jt][nt] = __builtin_amdgcn_mfma_f32_16x16x32_f16(afr[jt], bfr[nt], acc4[jt][nt], 0, 0, 0);
        }
    }
    __syncthreads();   // all aw reads complete before overwrite

    // ---- F[j][m] = E[j][m] * c[m] back into awF (swizzled) ----
    #pragma unroll
    for (int nt = 0; nt < 4; ++nt) {
        const int m = n0 + nt * 16 + (lane & 15);
        const float cm = cs[m];
        #pragma unroll
        for (int jt = 0; jt < 4; ++jt) {
            const int rowbase = jt * 16 + (lane >> 4) * 4;
            #pragma unroll
            for (int r = 0; r < 4; ++r) {
                const int j = rowbase + r;
                awF[j * HID + (((m >> 3) ^ (j & 7)) << 3) + (m & 7)] = (f16)(acc4[jt][nt][r] * cm);
            }
        }
    }
    __syncthreads();

    // ---- R GEMM: R[64 j][512 k] = F @ W2^T, wave owns k-tiles [wv*64, ...) ----
    #pragma unroll
    for (int a = 0; a < 4; ++a)
        #pragma unroll
        for (int c = 0; c < 4; ++c) acc4[a][c] = (f32x4){0.f, 0.f, 0.f, 0.f};
    {
        const f16* bptr = g_w2f + (size_t)(n0 + (lane & 15)) * HID + 8 * (lane >> 4);
        #pragma unroll 2
        for (int ms = 0; ms < 16; ++ms) {
            f16x8 afr[4], bfr[4];
            #pragma unroll
            for (int jt = 0; jt < 4; ++jt) {
                const int row = jt * 16 + (lane & 15);
                afr[jt] = awF8[row * 64 + ((ms * 4 + (lane >> 4)) ^ (row & 7))];
            }
            #pragma unroll
            for (int nt = 0; nt < 4; ++nt)
                bfr[nt] = *(const f16x8*)(bptr + nt * 16 * HID + ms * 32);
            #pragma unroll
            for (int jt = 0; jt < 4; ++jt)
                #pragma unroll
                for (int nt = 0; nt < 4; ++nt)
                    acc4[jt][nt] = __builtin_amdgcn_mfma_f32_16x16x32_f16(afr[jt], bfr[nt], acc4[jt][nt], 0, 0, 0);
        }
    }

    // ---- fold: base = R*t1 + s*W1x ; vq += W1q*base ; vp += W1p*base ----
    float vq[4][4], vp[4][4];
    #pragma unroll
    for (int a = 0; a < 4; ++a)
        #pragma unroll
        for (int r = 0; r < 4; ++r) { vq[a][r] = 0.f; vp[a][r] = 0.f; }

    #pragma unroll
    for (int nt = 0; nt < 4; ++nt) {
        const int k = n0 + nt * 16 + (lane & 15);
        const float t1k = t1s[k];
        const float sk  = ss[k];
        #pragma unroll
        for (int jt = 0; jt < 4; ++jt) {
            const int rowbase = jt * 16 + (lane >> 4) * 4;
            #pragma unroll
            for (int r = 0; r < 4; ++r) {
                const int j = rowbase + r;
                const float w1x = W1[(size_t)j * HID + k];
                const float w1q = W1[(size_t)(NQ + j) * HID + k];
                const float w1p = W1[(size_t)(2 * NQ + j) * HID + k];
                const float base = acc4[jt][nt][r] * t1k + sk * w1x;
                vq[jt][r] += w1q * base;
                vp[jt][r] += w1p * base;
            }
        }
    }

    // ---- reduce over the 16 k's held across lane&15, then across waves ----
    #pragma unroll
    for (int jt = 0; jt < 4; ++jt) {
        #pragma unroll
        for (int r = 0; r < 4; ++r) {
            float v = vq[jt][r], u2 = vp[jt][r];
            v  += __shfl_xor(v, 1, 64);  v  += __shfl_xor(v, 2, 64);
            v  += __shfl_xor(v, 4, 64);  v  += __shfl_xor(v, 8, 64);
            u2 += __shfl_xor(u2, 1, 64); u2 += __shfl_xor(u2, 2, 64);
            u2 += __shfl_xor(u2, 4, 64); u2 += __shfl_xor(u2, 8, 64);
            if ((lane & 15) == 0) {
                const int j = jt * 16 + (lane >> 4) * 4 + r;
                atomicAdd(&red[j][0], v);
                atomicAdd(&red[j][1], u2);
            }
        }
    }
    __syncthreads();

    if (tid < NQ) {
        // dH_dq_dx -> output 1 (p_dot_hat = -dH_dq_dx)
        out[(size_t)BATCH * NQ + (size_t)b * NQ + tid] = -red[tid][0];
    } else if (tid < 2 * NQ) {
        // dH_dp_dx -> output 0 (q_dot_hat = -dH_dp_dx)
        out[(size_t)b * NQ + (tid - NQ)] = -red[tid - NQ][1];
    }
}

extern "C" void kernel_launch(void* const* d_in, const int* in_sizes, int n_in,
                              void* d_out, int out_size, void* d_ws, size_t ws_size,
                              hipStream_t stream) {
    const float* x  = (const float*)d_in[0];
    const float* q  = (const float*)d_in[1];
    const float* p  = (const float*)d_in[2];
    const float* W1 = (const float*)d_in[3];
    const float* b1 = (const float*)d_in[4];
    const float* W2 = (const float*)d_in[5];
    const float* b2 = (const float*)d_in[6];
    const float* W3 = (const float*)d_in[7];
    float* out = (float*)d_out;

    prep_w2<<<HID, HID, 0, stream>>>(W2);
    hnn_mfma<<<BATCH, NT, 0, stream>>>(x, q, p, W1, b1, b2, W3, out);
}

// Round 3
// 1136.022 us; speedup vs baseline: 14.2133x; 2.1236x over previous
//
#include <hip/hip_runtime.h>

#define BATCH 8192
#define NQ 64          // spatial dim n
#define HID 512
#define DIN 192        // 3*n
#define NT 512         // threads per block (8 waves)
#define SPB1 16        // samples per block, fwd1
#define SPB2 32        // samples per block, fwd2/fwd3

typedef _Float16 f16;
typedef _Float16 f16x8 __attribute__((ext_vector_type(8)));
typedef float f32x4 __attribute__((ext_vector_type(4)));

// W2 in MFMA-fragment-major order (pre-swizzled global, coalesced 1KB frag loads)
__device__ f16 g_w2fragT[HID * HID];  // B-frag for C=A@W2   (cols m, contraction k)
__device__ f16 g_w2fragR[HID * HID];  // B-frag for C=A@W2^T (cols k, contraction m)
// per-sample forward intermediates
__device__ f16   g_h1[(size_t)BATCH * HID];
__device__ f16   g_v2[(size_t)BATCH * HID];
__device__ float g_t1[(size_t)BATCH * HID];
__device__ float g_n2h1t1[(size_t)BATCH * HID];
__device__ float g_c[(size_t)BATCH * HID];
__device__ float g_s[(size_t)BATCH * HID];

// ---------------- prep: fragment-major f16 W2 layouts ----------------
__global__ void prep_frag(const float* __restrict__ W2) {
    const int k = blockIdx.x;    // 512
    const int m = threadIdx.x;   // 512
    const f16 v = (f16)W2[k * HID + m];
    // frag value for A@W2: lane=(m&15)|(((k>>3)&3)<<4), n16=m>>4, ks=k>>5, e=k&7
    g_w2fragT[(size_t)((((m >> 4) * 16 + (k >> 5)) * 64) + ((m & 15) | (((k >> 3) & 3) << 4))) * 8 + (k & 7)] = v;
    // frag value for A@W2^T: lane=(k&15)|(((m>>3)&3)<<4), k16=k>>4, ms=m>>5, e=m&7
    g_w2fragR[(size_t)((((k >> 4) * 16 + (m >> 5)) * 64) + ((k & 15) | (((m >> 3) & 3) << 4))) * 8 + (m & 7)] = v;
}

// ---------------- fwd1: layer1 in fp32, batched over samples ----------------
__global__ __launch_bounds__(NT)
void fwd1(const float* __restrict__ x, const float* __restrict__ q,
          const float* __restrict__ p, const float* __restrict__ W1,
          const float* __restrict__ b1) {
    __shared__ float zs[SPB1][DIN];
    const int b0 = blockIdx.x * SPB1;
    const int tid = threadIdx.x;
    for (int i = tid; i < SPB1 * DIN; i += NT) {
        const int s = i / DIN, kk = i % DIN;
        float v;
        if (kk < NQ)          v = x[(b0 + s) * NQ + kk];
        else if (kk < 2 * NQ) v = q[(b0 + s) * NQ + kk - NQ];
        else                  v = p[(b0 + s) * NQ + kk - 2 * NQ];
        zs[s][kk] = v;
    }
    __syncthreads();
    const int m = tid;
    float acc[SPB1];
    #pragma unroll
    for (int s = 0; s < SPB1; ++s) acc[s] = 0.f;
    #pragma unroll 2
    for (int k = 0; k < DIN; ++k) {
        const float w = W1[k * HID + m];
        #pragma unroll
        for (int s = 0; s < SPB1; ++s) acc[s] += zs[s][k] * w;
    }
    const float bb = b1[m];
    #pragma unroll
    for (int s = 0; s < SPB1; ++s) {
        const float h1 = tanhf(acc[s] + bb);
        const float t1 = 1.f - h1 * h1;
        const size_t idx = (size_t)(b0 + s) * HID + m;
        g_h1[idx] = (f16)h1;
        g_t1[idx] = t1;
        g_n2h1t1[idx] = -2.f * h1 * t1;
    }
}

// ---------------- fwd2: H2 = tanh(H1@W2+b2) -> v2, c (32-sample MFMA tile) ----------------
__global__ __launch_bounds__(NT)
void fwd2(const float* __restrict__ b2, const float* __restrict__ W3) {
    __shared__ f16 alds[SPB2 * HID];
    const int b0 = blockIdx.x * SPB2;
    const int tid = threadIdx.x, lane = tid & 63, wv = tid >> 6;
    {
        const int s = tid >> 4;
        f16x8* a8 = (f16x8*)alds;
        #pragma unroll
        for (int c = 0; c < 4; ++c) {
            const int kc = (tid & 15) + c * 16;
            const f16x8 v = *(const f16x8*)&g_h1[(size_t)(b0 + s) * HID + kc * 8];
            a8[s * 64 + (kc ^ (s & 7))] = v;
        }
    }
    __syncthreads();
    const int n0 = wv * 64;
    f32x4 acc[2][4];
    #pragma unroll
    for (int a = 0; a < 2; ++a)
        #pragma unroll
        for (int c = 0; c < 4; ++c) acc[a][c] = (f32x4){0.f, 0.f, 0.f, 0.f};
    const f16x8* a8 = (const f16x8*)alds;
    #pragma unroll 2
    for (int ks = 0; ks < 16; ++ks) {
        f16x8 afr[2], bfr[4];
        #pragma unroll
        for (int jt = 0; jt < 2; ++jt) {
            const int row = jt * 16 + (lane & 15);
            afr[jt] = a8[row * 64 + ((ks * 4 + (lane >> 4)) ^ (row & 7))];
        }
        #pragma unroll
        for (int nt = 0; nt < 4; ++nt)
            bfr[nt] = *(const f16x8*)&g_w2fragT[(size_t)((((wv * 4 + nt) * 16 + ks) * 64) + lane) * 8];
        #pragma unroll
        for (int jt = 0; jt < 2; ++jt)
            #pragma unroll
            for (int nt = 0; nt < 4; ++nt)
                acc[jt][nt] = __builtin_amdgcn_mfma_f32_16x16x32_f16(afr[jt], bfr[nt], acc[jt][nt], 0, 0, 0);
    }
    #pragma unroll
    for (int nt = 0; nt < 4; ++nt) {
        const int mcol = n0 + nt * 16 + (lane & 15);
        const float bb = b2[mcol], w3 = W3[mcol];
        #pragma unroll
        for (int jt = 0; jt < 2; ++jt) {
            #pragma unroll
            for (int r = 0; r < 4; ++r) {
                const int srow = jt * 16 + (lane >> 4) * 4 + r;
                const float h2 = tanhf(acc[jt][nt][r] + bb);
                const float t2 = 1.f - h2 * h2;
                const float v2 = w3 * t2;
                const size_t idx = (size_t)(b0 + srow) * HID + mcol;
                g_v2[idx] = (f16)v2;
                g_c[idx] = -2.f * h2 * v2;
            }
        }
    }
}

// ---------------- fwd3: U = V2@W2^T ; s = -2 h1 t1 u ----------------
__global__ __launch_bounds__(NT)
void fwd3() {
    __shared__ f16 alds[SPB2 * HID];
    const int b0 = blockIdx.x * SPB2;
    const int tid = threadIdx.x, lane = tid & 63, wv = tid >> 6;
    {
        const int s = tid >> 4;
        f16x8* a8 = (f16x8*)alds;
        #pragma unroll
        for (int c = 0; c < 4; ++c) {
            const int kc = (tid & 15) + c * 16;
            const f16x8 v = *(const f16x8*)&g_v2[(size_t)(b0 + s) * HID + kc * 8];
            a8[s * 64 + (kc ^ (s & 7))] = v;
        }
    }
    __syncthreads();
    const int n0 = wv * 64;
    f32x4 acc[2][4];
    #pragma unroll
    for (int a = 0; a < 2; ++a)
        #pragma unroll
        for (int c = 0; c < 4; ++c) acc[a][c] = (f32x4){0.f, 0.f, 0.f, 0.f};
    const f16x8* a8 = (const f16x8*)alds;
    #pragma unroll 2
    for (int ms = 0; ms < 16; ++ms) {
        f16x8 afr[2], bfr[4];
        #pragma unroll
        for (int jt = 0; jt < 2; ++jt) {
            const int row = jt * 16 + (lane & 15);
            afr[jt] = a8[row * 64 + ((ms * 4 + (lane >> 4)) ^ (row & 7))];
        }
        #pragma unroll
        for (int nt = 0; nt < 4; ++nt)
            bfr[nt] = *(const f16x8*)&g_w2fragR[(size_t)((((wv * 4 + nt) * 16 + ms) * 64) + lane) * 8];
        #pragma unroll
        for (int jt = 0; jt < 2; ++jt)
            #pragma unroll
            for (int nt = 0; nt < 4; ++nt)
                acc[jt][nt] = __builtin_amdgcn_mfma_f32_16x16x32_f16(afr[jt], bfr[nt], acc[jt][nt], 0, 0, 0);
    }
    #pragma unroll
    for (int nt = 0; nt < 4; ++nt) {
        const int kcol = n0 + nt * 16 + (lane & 15);
        #pragma unroll
        for (int jt = 0; jt < 2; ++jt) {
            #pragma unroll
            for (int r = 0; r < 4; ++r) {
                const int srow = jt * 16 + (lane >> 4) * 4 + r;
                const size_t idx = (size_t)(b0 + srow) * HID + kcol;
                g_s[idx] = g_n2h1t1[idx] * acc[jt][nt][r];
            }
        }
    }
}

// ---------------- main: per-sample E-GEMM -> F -> R-GEMM -> fold ----------------
__global__ __launch_bounds__(NT)
void hnn_main(const float* __restrict__ W1, float* __restrict__ out) {
    __shared__ f16 awF[NQ * HID];          // 64KB: aw (=W1_x * t1), then F (=E*c)
    __shared__ float t1s[HID], cs[HID], ss[HID];
    __shared__ float red[NQ][2];

    const int tid = threadIdx.x, lane = tid & 63, wv = tid >> 6;
    const int b = blockIdx.x;

    if (tid < 2 * NQ) ((float*)red)[tid] = 0.f;
    t1s[tid] = g_t1[(size_t)b * HID + tid];
    cs[tid]  = g_c[(size_t)b * HID + tid];
    ss[tid]  = g_s[(size_t)b * HID + tid];
    __syncthreads();

    // build aw[j][k] = W1[x_j,k] * t1[k] in f16, XOR-swizzled 16B chunks
    {
        const int j  = tid & 63;
        const int cg = tid >> 6;
        const float* w1row = W1 + (size_t)j * HID;
        f16x8* aw8 = (f16x8*)awF;
        #pragma unroll
        for (int c = 0; c < 8; ++c) {
            const int kc = cg * 8 + c, col0 = kc * 8;
            float4 wa = *(const float4*)(w1row + col0);
            float4 wb = *(const float4*)(w1row + col0 + 4);
            float4 ta = *(const float4*)(t1s + col0);
            float4 tb = *(const float4*)(t1s + col0 + 4);
            f16x8 h;
            h[0] = (f16)(wa.x * ta.x); h[1] = (f16)(wa.y * ta.y);
            h[2] = (f16)(wa.z * ta.z); h[3] = (f16)(wa.w * ta.w);
            h[4] = (f16)(wb.x * tb.x); h[5] = (f16)(wb.y * tb.y);
            h[6] = (f16)(wb.z * tb.z); h[7] = (f16)(wb.w * tb.w);
            aw8[j * 64 + (kc ^ (j & 7))] = h;
        }
    }
    __syncthreads();

    const int n0 = wv * 64;
    f32x4 acc4[4][4];
    #pragma unroll
    for (int a = 0; a < 4; ++a)
        #pragma unroll
        for (int c = 0; c < 4; ++c) acc4[a][c] = (f32x4){0.f, 0.f, 0.f, 0.f};
    const f16x8* awF8 = (const f16x8*)awF;

    // E GEMM: E[64 j][512 m] = aw @ W2
    #pragma unroll 2
    for (int ks = 0; ks < 16; ++ks) {
        f16x8 afr[4], bfr[4];
        #pragma unroll
        for (int jt = 0; jt < 4; ++jt) {
            const int row = jt * 16 + (lane & 15);
            afr[jt] = awF8[row * 64 + ((ks * 4 + (lane >> 4)) ^ (row & 7))];
        }
        #pragma unroll
        for (int nt = 0; nt < 4; ++nt)
            bfr[nt] = *(const f16x8*)&g_w2fragT[(size_t)((((wv * 4 + nt) * 16 + ks) * 64) + lane) * 8];
        #pragma unroll
        for (int jt = 0; jt < 4; ++jt)
            #pragma unroll
            for (int nt = 0; nt < 4; ++nt)
                acc4[jt][nt] = __builtin_amdgcn_mfma_f32_16x16x32_f16(afr[jt], bfr[nt], acc4[jt][nt], 0, 0, 0);
    }
    __syncthreads();

    // F[j][m] = E[j][m] * c[m] back into awF (swizzled)
    #pragma unroll
    for (int nt = 0; nt < 4; ++nt) {
        const int m = n0 + nt * 16 + (lane & 15);
        const float cm = cs[m];
        #pragma unroll
        for (int jt = 0; jt < 4; ++jt) {
            const int rowbase = jt * 16 + (lane >> 4) * 4;
            #pragma unroll
            for (int r = 0; r < 4; ++r) {
                const int j = rowbase + r;
                awF[j * HID + (((m >> 3) ^ (j & 7)) << 3) + (m & 7)] = (f16)(acc4[jt][nt][r] * cm);
            }
        }
    }
    __syncthreads();

    // R GEMM: R[64 j][512 k] = F @ W2^T
    #pragma unroll
    for (int a = 0; a < 4; ++a)
        #pragma unroll
        for (int c = 0; c < 4; ++c) acc4[a][c] = (f32x4){0.f, 0.f, 0.f, 0.f};
    #pragma unroll 2
    for (int ms = 0; ms < 16; ++ms) {
        f16x8 afr[4], bfr[4];
        #pragma unroll
        for (int jt = 0; jt < 4; ++jt) {
            const int row = jt * 16 + (lane & 15);
            afr[jt] = awF8[row * 64 + ((ms * 4 + (lane >> 4)) ^ (row & 7))];
        }
        #pragma unroll
        for (int nt = 0; nt < 4; ++nt)
            bfr[nt] = *(const f16x8*)&g_w2fragR[(size_t)((((wv * 4 + nt) * 16 + ms) * 64) + lane) * 8];
        #pragma unroll
        for (int jt = 0; jt < 4; ++jt)
            #pragma unroll
            for (int nt = 0; nt < 4; ++nt)
                acc4[jt][nt] = __builtin_amdgcn_mfma_f32_16x16x32_f16(afr[jt], bfr[nt], acc4[jt][nt], 0, 0, 0);
    }

    // fold: base = R*t1 + s*W1x ; vq += W1q*base ; vp += W1p*base
    float vq[4][4], vp[4][4];
    #pragma unroll
    for (int a = 0; a < 4; ++a)
        #pragma unroll
        for (int r = 0; r < 4; ++r) { vq[a][r] = 0.f; vp[a][r] = 0.f; }

    #pragma unroll
    for (int nt = 0; nt < 4; ++nt) {
        const int k = n0 + nt * 16 + (lane & 15);
        const float t1k = t1s[k];
        const float sk  = ss[k];
        #pragma unroll
        for (int jt = 0; jt < 4; ++jt) {
            const int rowbase = jt * 16 + (lane >> 4) * 4;
            #pragma unroll
            for (int r = 0; r < 4; ++r) {
                const int j = rowbase + r;
                const float w1x = W1[(size_t)j * HID + k];
                const float w1q = W1[(size_t)(NQ + j) * HID + k];
                const float w1p = W1[(size_t)(2 * NQ + j) * HID + k];
                const float base = acc4[jt][nt][r] * t1k + sk * w1x;
                vq[jt][r] += w1q * base;
                vp[jt][r] += w1p * base;
            }
        }
    }

    #pragma unroll
    for (int jt = 0; jt < 4; ++jt) {
        #pragma unroll
        for (int r = 0; r < 4; ++r) {
            float v = vq[jt][r], u2 = vp[jt][r];
            v  += __shfl_xor(v, 1, 64);  v  += __shfl_xor(v, 2, 64);
            v  += __shfl_xor(v, 4, 64);  v  += __shfl_xor(v, 8, 64);
            u2 += __shfl_xor(u2, 1, 64); u2 += __shfl_xor(u2, 2, 64);
            u2 += __shfl_xor(u2, 4, 64); u2 += __shfl_xor(u2, 8, 64);
            if ((lane & 15) == 0) {
                const int j = jt * 16 + (lane >> 4) * 4 + r;
                atomicAdd(&red[j][0], v);
                atomicAdd(&red[j][1], u2);
            }
        }
    }
    __syncthreads();

    if (tid < NQ) {
        out[(size_t)BATCH * NQ + (size_t)b * NQ + tid] = -red[tid][0];   // p_dot = -dH_dq_dx
    } else if (tid < 2 * NQ) {
        out[(size_t)b * NQ + (tid - NQ)] = -red[tid - NQ][1];            // q_dot = -dH_dp_dx
    }
}

extern "C" void kernel_launch(void* const* d_in, const int* in_sizes, int n_in,
                              void* d_out, int out_size, void* d_ws, size_t ws_size,
                              hipStream_t stream) {
    const float* x  = (const float*)d_in[0];
    const float* q  = (const float*)d_in[1];
    const float* p  = (const float*)d_in[2];
    const float* W1 = (const float*)d_in[3];
    const float* b1 = (const float*)d_in[4];
    const float* W2 = (const float*)d_in[5];
    const float* b2 = (const float*)d_in[6];
    const float* W3 = (const float*)d_in[7];
    float* out = (float*)d_out;

    prep_frag<<<HID, HID, 0, stream>>>(W2);
    fwd1<<<BATCH / SPB1, NT, 0, stream>>>(x, q, p, W1, b1);
    fwd2<<<BATCH / SPB2, NT, 0, stream>>>(b2, W3);
    fwd3<<<BATCH / SPB2, NT, 0, stream>>>();
    hnn_main<<<BATCH, NT, 0, stream>>>(W1, out);
}

// Round 4
// 876.559 us; speedup vs baseline: 18.4204x; 1.2960x over previous
//
#include <hip/hip_runtime.h>

#define BATCH 8192
#define NQ 64          // spatial dim n
#define HID 512
#define DIN 192        // 3*n
#define NT 512         // threads per block (8 waves)
#define SPB1 16        // samples per block, fwd1
#define SPB2 32        // samples per block, fwd2/fwd3

typedef _Float16 f16;
typedef _Float16 f16x8 __attribute__((ext_vector_type(8)));
typedef float f32x4 __attribute__((ext_vector_type(4)));

// W2 in MFMA-fragment-major order (pre-swizzled global, coalesced 1KB frag loads)
__device__ f16 g_w2fragT[HID * HID];  // B-frag for C=A@W2   (cols m, contraction k)
__device__ f16 g_w2fragR[HID * HID];  // B-frag for C=A@W2^T (cols k, contraction m)
// per-sample forward intermediates
__device__ f16   g_h1[(size_t)BATCH * HID];
__device__ f16   g_v2[(size_t)BATCH * HID];
__device__ float g_t1[(size_t)BATCH * HID];
__device__ float g_n2h1t1[(size_t)BATCH * HID];
__device__ float g_c[(size_t)BATCH * HID];
__device__ float g_s[(size_t)BATCH * HID];

// ---------------- prep: fragment-major f16 W2 layouts ----------------
__global__ void prep_frag(const float* __restrict__ W2) {
    const int k = blockIdx.x;    // 512
    const int m = threadIdx.x;   // 512
    const f16 v = (f16)W2[k * HID + m];
    g_w2fragT[(size_t)((((m >> 4) * 16 + (k >> 5)) * 64) + ((m & 15) | (((k >> 3) & 3) << 4))) * 8 + (k & 7)] = v;
    g_w2fragR[(size_t)((((k >> 4) * 16 + (m >> 5)) * 64) + ((k & 15) | (((m >> 3) & 3) << 4))) * 8 + (m & 7)] = v;
}

// ---------------- fwd1: layer1 in fp32, batched over samples ----------------
__global__ __launch_bounds__(NT)
void fwd1(const float* __restrict__ x, const float* __restrict__ q,
          const float* __restrict__ p, const float* __restrict__ W1,
          const float* __restrict__ b1) {
    __shared__ float zs[SPB1][DIN];
    const int b0 = blockIdx.x * SPB1;
    const int tid = threadIdx.x;
    for (int i = tid; i < SPB1 * DIN; i += NT) {
        const int s = i / DIN, kk = i % DIN;
        float v;
        if (kk < NQ)          v = x[(b0 + s) * NQ + kk];
        else if (kk < 2 * NQ) v = q[(b0 + s) * NQ + kk - NQ];
        else                  v = p[(b0 + s) * NQ + kk - 2 * NQ];
        zs[s][kk] = v;
    }
    __syncthreads();
    const int m = tid;
    float acc[SPB1];
    #pragma unroll
    for (int s = 0; s < SPB1; ++s) acc[s] = 0.f;
    #pragma unroll 2
    for (int k = 0; k < DIN; ++k) {
        const float w = W1[k * HID + m];
        #pragma unroll
        for (int s = 0; s < SPB1; ++s) acc[s] += zs[s][k] * w;
    }
    const float bb = b1[m];
    #pragma unroll
    for (int s = 0; s < SPB1; ++s) {
        const float h1 = tanhf(acc[s] + bb);
        const float t1 = 1.f - h1 * h1;
        const size_t idx = (size_t)(b0 + s) * HID + m;
        g_h1[idx] = (f16)h1;
        g_t1[idx] = t1;
        g_n2h1t1[idx] = -2.f * h1 * t1;
    }
}

// ---------------- fwd2: H2 = tanh(H1@W2+b2) -> v2, c (32-sample MFMA tile) ----------------
__global__ __launch_bounds__(NT)
void fwd2(const float* __restrict__ b2, const float* __restrict__ W3) {
    __shared__ f16 alds[SPB2 * HID];
    const int b0 = blockIdx.x * SPB2;
    const int tid = threadIdx.x, lane = tid & 63, wv = tid >> 6;
    {
        const int s = tid >> 4;
        f16x8* a8 = (f16x8*)alds;
        #pragma unroll
        for (int c = 0; c < 4; ++c) {
            const int kc = (tid & 15) + c * 16;
            const f16x8 v = *(const f16x8*)&g_h1[(size_t)(b0 + s) * HID + kc * 8];
            a8[s * 64 + (kc ^ (s & 7))] = v;
        }
    }
    __syncthreads();
    const int n0 = wv * 64;
    f32x4 acc[2][4];
    #pragma unroll
    for (int a = 0; a < 2; ++a)
        #pragma unroll
        for (int c = 0; c < 4; ++c) acc[a][c] = (f32x4){0.f, 0.f, 0.f, 0.f};
    const f16x8* a8 = (const f16x8*)alds;
    #pragma unroll 2
    for (int ks = 0; ks < 16; ++ks) {
        f16x8 afr[2], bfr[4];
        #pragma unroll
        for (int jt = 0; jt < 2; ++jt) {
            const int row = jt * 16 + (lane & 15);
            afr[jt] = a8[row * 64 + ((ks * 4 + (lane >> 4)) ^ (row & 7))];
        }
        #pragma unroll
        for (int nt = 0; nt < 4; ++nt)
            bfr[nt] = *(const f16x8*)&g_w2fragT[(size_t)((((wv * 4 + nt) * 16 + ks) * 64) + lane) * 8];
        #pragma unroll
        for (int jt = 0; jt < 2; ++jt)
            #pragma unroll
            for (int nt = 0; nt < 4; ++nt)
                acc[jt][nt] = __builtin_amdgcn_mfma_f32_16x16x32_f16(afr[jt], bfr[nt], acc[jt][nt], 0, 0, 0);
    }
    #pragma unroll
    for (int nt = 0; nt < 4; ++nt) {
        const int mcol = n0 + nt * 16 + (lane & 15);
        const float bb = b2[mcol], w3 = W3[mcol];
        #pragma unroll
        for (int jt = 0; jt < 2; ++jt) {
            #pragma unroll
            for (int r = 0; r < 4; ++r) {
                const int srow = jt * 16 + (lane >> 4) * 4 + r;
                const float h2 = tanhf(acc[jt][nt][r] + bb);
                const float t2 = 1.f - h2 * h2;
                const float v2 = w3 * t2;
                const size_t idx = (size_t)(b0 + srow) * HID + mcol;
                g_v2[idx] = (f16)v2;
                g_c[idx] = -2.f * h2 * v2;
            }
        }
    }
}

// ---------------- fwd3: U = V2@W2^T ; s = -2 h1 t1 u ----------------
__global__ __launch_bounds__(NT)
void fwd3() {
    __shared__ f16 alds[SPB2 * HID];
    const int b0 = blockIdx.x * SPB2;
    const int tid = threadIdx.x, lane = tid & 63, wv = tid >> 6;
    {
        const int s = tid >> 4;
        f16x8* a8 = (f16x8*)alds;
        #pragma unroll
        for (int c = 0; c < 4; ++c) {
            const int kc = (tid & 15) + c * 16;
            const f16x8 v = *(const f16x8*)&g_v2[(size_t)(b0 + s) * HID + kc * 8];
            a8[s * 64 + (kc ^ (s & 7))] = v;
        }
    }
    __syncthreads();
    const int n0 = wv * 64;
    f32x4 acc[2][4];
    #pragma unroll
    for (int a = 0; a < 2; ++a)
        #pragma unroll
        for (int c = 0; c < 4; ++c) acc[a][c] = (f32x4){0.f, 0.f, 0.f, 0.f};
    const f16x8* a8 = (const f16x8*)alds;
    #pragma unroll 2
    for (int ms = 0; ms < 16; ++ms) {
        f16x8 afr[2], bfr[4];
        #pragma unroll
        for (int jt = 0; jt < 2; ++jt) {
            const int row = jt * 16 + (lane & 15);
            afr[jt] = a8[row * 64 + ((ms * 4 + (lane >> 4)) ^ (row & 7))];
        }
        #pragma unroll
        for (int nt = 0; nt < 4; ++nt)
            bfr[nt] = *(const f16x8*)&g_w2fragR[(size_t)((((wv * 4 + nt) * 16 + ms) * 64) + lane) * 8];
        #pragma unroll
        for (int jt = 0; jt < 2; ++jt)
            #pragma unroll
            for (int nt = 0; nt < 4; ++nt)
                acc[jt][nt] = __builtin_amdgcn_mfma_f32_16x16x32_f16(afr[jt], bfr[nt], acc[jt][nt], 0, 0, 0);
    }
    #pragma unroll
    for (int nt = 0; nt < 4; ++nt) {
        const int kcol = n0 + nt * 16 + (lane & 15);
        #pragma unroll
        for (int jt = 0; jt < 2; ++jt) {
            #pragma unroll
            for (int r = 0; r < 4; ++r) {
                const int srow = jt * 16 + (lane >> 4) * 4 + r;
                const size_t idx = (size_t)(b0 + srow) * HID + kcol;
                g_s[idx] = g_n2h1t1[idx] * acc[jt][nt][r];
            }
        }
    }
}

// ---------------- main: per-sample E-GEMM -> F -> R-GEMM -> fold ----------------
__global__ __launch_bounds__(NT, 2)   // cap 256 VGPR: no spill (R2 spilled 540MB at 128)
void hnn_main(const float* __restrict__ W1, float* __restrict__ out) {
    __shared__ f16 awF[NQ * HID];          // 64KB: aw (=W1_x * t1), then F (=E*c)
    __shared__ float t1s[HID], cs[HID], ss[HID];
    __shared__ float red[NQ][2];

    const int tid = threadIdx.x, lane = tid & 63, wv = tid >> 6;
    const int b = blockIdx.x;

    if (tid < 2 * NQ) ((float*)red)[tid] = 0.f;
    t1s[tid] = g_t1[(size_t)b * HID + tid];
    cs[tid]  = g_c[(size_t)b * HID + tid];
    ss[tid]  = g_s[(size_t)b * HID + tid];
    __syncthreads();

    // build aw[j][k] = W1[x_j,k] * t1[k] in f16, XOR-swizzled 16B chunks
    {
        const int j  = tid & 63;
        const int cg = tid >> 6;
        const float* w1row = W1 + (size_t)j * HID;
        f16x8* aw8 = (f16x8*)awF;
        #pragma unroll
        for (int c = 0; c < 8; ++c) {
            const int kc = cg * 8 + c, col0 = kc * 8;
            float4 wa = *(const float4*)(w1row + col0);
            float4 wb = *(const float4*)(w1row + col0 + 4);
            float4 ta = *(const float4*)(t1s + col0);
            float4 tb = *(const float4*)(t1s + col0 + 4);
            f16x8 h;
            h[0] = (f16)(wa.x * ta.x); h[1] = (f16)(wa.y * ta.y);
            h[2] = (f16)(wa.z * ta.z); h[3] = (f16)(wa.w * ta.w);
            h[4] = (f16)(wb.x * tb.x); h[5] = (f16)(wb.y * tb.y);
            h[6] = (f16)(wb.z * tb.z); h[7] = (f16)(wb.w * tb.w);
            aw8[j * 64 + (kc ^ (j & 7))] = h;
        }
    }
    __syncthreads();

    const int n0 = wv * 64;
    f32x4 acc4[4][4];
    #pragma unroll
    for (int a = 0; a < 4; ++a)
        #pragma unroll
        for (int c = 0; c < 4; ++c) acc4[a][c] = (f32x4){0.f, 0.f, 0.f, 0.f};
    const f16x8* awF8 = (const f16x8*)awF;

    // E GEMM: E[64 j][512 m] = aw @ W2
    #pragma unroll 2
    for (int ks = 0; ks < 16; ++ks) {
        f16x8 afr[4], bfr[4];
        #pragma unroll
        for (int jt = 0; jt < 4; ++jt) {
            const int row = jt * 16 + (lane & 15);
            afr[jt] = awF8[row * 64 + ((ks * 4 + (lane >> 4)) ^ (row & 7))];
        }
        #pragma unroll
        for (int nt = 0; nt < 4; ++nt)
            bfr[nt] = *(const f16x8*)&g_w2fragT[(size_t)((((wv * 4 + nt) * 16 + ks) * 64) + lane) * 8];
        #pragma unroll
        for (int jt = 0; jt < 4; ++jt)
            #pragma unroll
            for (int nt = 0; nt < 4; ++nt)
                acc4[jt][nt] = __builtin_amdgcn_mfma_f32_16x16x32_f16(afr[jt], bfr[nt], acc4[jt][nt], 0, 0, 0);
    }
    __syncthreads();

    // F[j][m] = E[j][m] * c[m] back into awF (swizzled)
    #pragma unroll
    for (int nt = 0; nt < 4; ++nt) {
        const int m = n0 + nt * 16 + (lane & 15);
        const float cm = cs[m];
        #pragma unroll
        for (int jt = 0; jt < 4; ++jt) {
            const int rowbase = jt * 16 + (lane >> 4) * 4;
            #pragma unroll
            for (int r = 0; r < 4; ++r) {
                const int j = rowbase + r;
                awF[j * HID + (((m >> 3) ^ (j & 7)) << 3) + (m & 7)] = (f16)(acc4[jt][nt][r] * cm);
            }
        }
    }
    __syncthreads();

    // R GEMM: R[64 j][512 k] = F @ W2^T
    #pragma unroll
    for (int a = 0; a < 4; ++a)
        #pragma unroll
        for (int c = 0; c < 4; ++c) acc4[a][c] = (f32x4){0.f, 0.f, 0.f, 0.f};
    #pragma unroll 2
    for (int ms = 0; ms < 16; ++ms) {
        f16x8 afr[4], bfr[4];
        #pragma unroll
        for (int jt = 0; jt < 4; ++jt) {
            const int row = jt * 16 + (lane & 15);
            afr[jt] = awF8[row * 64 + ((ms * 4 + (lane >> 4)) ^ (row & 7))];
        }
        #pragma unroll
        for (int nt = 0; nt < 4; ++nt)
            bfr[nt] = *(const f16x8*)&g_w2fragR[(size_t)((((wv * 4 + nt) * 16 + ms) * 64) + lane) * 8];
        #pragma unroll
        for (int jt = 0; jt < 4; ++jt)
            #pragma unroll
            for (int nt = 0; nt < 4; ++nt)
                acc4[jt][nt] = __builtin_amdgcn_mfma_f32_16x16x32_f16(afr[jt], bfr[nt], acc4[jt][nt], 0, 0, 0);
    }

    // fold: base = R*t1 + s*W1x ; vq = sum W1q*base ; vp = sum W1p*base
    // (scalars per (jt,r), reduced immediately — no 32-float spill arrays)
    float t1k[4], sk[4];
    #pragma unroll
    for (int nt = 0; nt < 4; ++nt) {
        const int k = n0 + nt * 16 + (lane & 15);
        t1k[nt] = t1s[k];
        sk[nt]  = ss[k];
    }
    #pragma unroll
    for (int jt = 0; jt < 4; ++jt) {
        #pragma unroll
        for (int r = 0; r < 4; ++r) {
            const int j = jt * 16 + (lane >> 4) * 4 + r;
            float vq = 0.f, vp = 0.f;
            #pragma unroll
            for (int nt = 0; nt < 4; ++nt) {
                const int k = n0 + nt * 16 + (lane & 15);
                const float w1x = W1[(size_t)j * HID + k];
                const float w1q = W1[(size_t)(NQ + j) * HID + k];
                const float w1p = W1[(size_t)(2 * NQ + j) * HID + k];
                const float base = acc4[jt][nt][r] * t1k[nt] + sk[nt] * w1x;
                vq += w1q * base;
                vp += w1p * base;
            }
            vq += __shfl_xor(vq, 1, 64); vq += __shfl_xor(vq, 2, 64);
            vq += __shfl_xor(vq, 4, 64); vq += __shfl_xor(vq, 8, 64);
            vp += __shfl_xor(vp, 1, 64); vp += __shfl_xor(vp, 2, 64);
            vp += __shfl_xor(vp, 4, 64); vp += __shfl_xor(vp, 8, 64);
            if ((lane & 15) == 0) {
                atomicAdd(&red[j][0], vq);
                atomicAdd(&red[j][1], vp);
            }
        }
    }
    __syncthreads();

    if (tid < NQ) {
        out[(size_t)BATCH * NQ + (size_t)b * NQ + tid] = -red[tid][0];   // p_dot = -dH_dq_dx
    } else if (tid < 2 * NQ) {
        out[(size_t)b * NQ + (tid - NQ)] = -red[tid - NQ][1];            // q_dot = -dH_dp_dx
    }
}

extern "C" void kernel_launch(void* const* d_in, const int* in_sizes, int n_in,
                              void* d_out, int out_size, void* d_ws, size_t ws_size,
                              hipStream_t stream) {
    const float* x  = (const float*)d_in[0];
    const float* q  = (const float*)d_in[1];
    const float* p  = (const float*)d_in[2];
    const float* W1 = (const float*)d_in[3];
    const float* b1 = (const float*)d_in[4];
    const float* W2 = (const float*)d_in[5];
    const float* b2 = (const float*)d_in[6];
    const float* W3 = (const float*)d_in[7];
    float* out = (float*)d_out;

    prep_frag<<<HID, HID, 0, stream>>>(W2);
    fwd1<<<BATCH / SPB1, NT, 0, stream>>>(x, q, p, W1, b1);
    fwd2<<<BATCH / SPB2, NT, 0, stream>>>(b2, W3);
    fwd3<<<BATCH / SPB2, NT, 0, stream>>>();
    hnn_main<<<BATCH, NT, 0, stream>>>(W1, out);
}

// Round 5
// 778.806 us; speedup vs baseline: 20.7325x; 1.1255x over previous
//
#include <hip/hip_runtime.h>

#define BATCH 8192
#define NQ 64          // spatial dim n
#define HID 512
#define DIN 192        // 3*n
#define NT 512         // threads per block (8 waves)
#define SPB1 16        // samples per block, fwd1
#define SPB2 32        // samples per block, fwd2/fwd3

typedef _Float16 f16;
typedef _Float16 f16x8 __attribute__((ext_vector_type(8)));
typedef float f32x4 __attribute__((ext_vector_type(4)));

// W2 in MFMA-fragment-major order (pre-swizzled global, coalesced 1KB frag loads)
__device__ f16 g_w2fragT[HID * HID];  // B-frag for C=A@W2   (cols m, contraction k)
__device__ f16 g_w2fragR[HID * HID];  // B-frag for C=A@W2^T (cols k, contraction m)
// per-sample forward intermediates
__device__ f16   g_h1[(size_t)BATCH * HID];
__device__ f16   g_v2[(size_t)BATCH * HID];
__device__ float g_t1[(size_t)BATCH * HID];
__device__ float g_n2h1t1[(size_t)BATCH * HID];
__device__ float g_c[(size_t)BATCH * HID];
__device__ float g_s[(size_t)BATCH * HID];

// ---------------- prep: fragment-major f16 W2 layouts ----------------
__global__ void prep_frag(const float* __restrict__ W2) {
    const int k = blockIdx.x;    // 512
    const int m = threadIdx.x;   // 512
    const f16 v = (f16)W2[k * HID + m];
    g_w2fragT[(size_t)((((m >> 4) * 16 + (k >> 5)) * 64) + ((m & 15) | (((k >> 3) & 3) << 4))) * 8 + (k & 7)] = v;
    g_w2fragR[(size_t)((((k >> 4) * 16 + (m >> 5)) * 64) + ((k & 15) | (((m >> 3) & 3) << 4))) * 8 + (m & 7)] = v;
}

// ---------------- fwd1: layer1 in fp32, batched over samples ----------------
__global__ __launch_bounds__(NT)
void fwd1(const float* __restrict__ x, const float* __restrict__ q,
          const float* __restrict__ p, const float* __restrict__ W1,
          const float* __restrict__ b1) {
    __shared__ float zs[SPB1][DIN];
    const int b0 = blockIdx.x * SPB1;
    const int tid = threadIdx.x;
    for (int i = tid; i < SPB1 * DIN; i += NT) {
        const int s = i / DIN, kk = i % DIN;
        float v;
        if (kk < NQ)          v = x[(b0 + s) * NQ + kk];
        else if (kk < 2 * NQ) v = q[(b0 + s) * NQ + kk - NQ];
        else                  v = p[(b0 + s) * NQ + kk - 2 * NQ];
        zs[s][kk] = v;
    }
    __syncthreads();
    const int m = tid;
    float acc[SPB1];
    #pragma unroll
    for (int s = 0; s < SPB1; ++s) acc[s] = 0.f;
    #pragma unroll 2
    for (int k = 0; k < DIN; ++k) {
        const float w = W1[k * HID + m];
        #pragma unroll
        for (int s = 0; s < SPB1; ++s) acc[s] += zs[s][k] * w;
    }
    const float bb = b1[m];
    #pragma unroll
    for (int s = 0; s < SPB1; ++s) {
        const float h1 = tanhf(acc[s] + bb);
        const float t1 = 1.f - h1 * h1;
        const size_t idx = (size_t)(b0 + s) * HID + m;
        g_h1[idx] = (f16)h1;
        g_t1[idx] = t1;
        g_n2h1t1[idx] = -2.f * h1 * t1;
    }
}

// ---------------- fwd2: H2 = tanh(H1@W2+b2) -> v2, c (32-sample MFMA tile) ----------------
__global__ __launch_bounds__(NT)
void fwd2(const float* __restrict__ b2, const float* __restrict__ W3) {
    __shared__ f16 alds[SPB2 * HID];
    const int b0 = blockIdx.x * SPB2;
    const int tid = threadIdx.x, lane = tid & 63, wv = tid >> 6;
    const int l15 = lane & 15, qd = lane >> 4;
    {
        const int s = tid >> 4;
        f16x8* a8 = (f16x8*)alds;
        #pragma unroll
        for (int c = 0; c < 4; ++c) {
            const int kc = (tid & 15) + c * 16;
            const f16x8 v = *(const f16x8*)&g_h1[(size_t)(b0 + s) * HID + kc * 8];
            a8[s * 64 + (kc ^ (s & 7))] = v;
        }
    }
    __syncthreads();
    const int n0 = wv * 64;
    f32x4 acc[2][4];
    #pragma unroll
    for (int a = 0; a < 2; ++a)
        #pragma unroll
        for (int c = 0; c < 4; ++c) acc[a][c] = (f32x4){0.f, 0.f, 0.f, 0.f};
    const f16x8* a8 = (const f16x8*)alds;

    auto aload = [&](f16x8* AF, int kn) {
        #pragma unroll
        for (int jt = 0; jt < 2; ++jt) {
            const int row = jt * 16 + l15;
            AF[jt] = a8[row * 64 + ((kn * 4 + qd) ^ (row & 7))];
        }
    };
    auto bload = [&](f16x8* BF, int kn) {
        #pragma unroll
        for (int nt = 0; nt < 4; ++nt)
            BF[nt] = *(const f16x8*)&g_w2fragT[(size_t)((((wv * 4 + nt) * 16 + kn) * 64) + lane) * 8];
    };
    auto cluster = [&](const f16x8* AF, const f16x8* BF) {
        #pragma unroll
        for (int jt = 0; jt < 2; ++jt)
            #pragma unroll
            for (int nt = 0; nt < 4; ++nt)
                acc[jt][nt] = __builtin_amdgcn_mfma_f32_16x16x32_f16(AF[jt], BF[nt], acc[jt][nt], 0, 0, 0);
    };

    f16x8 aA[2], bA[4], aB[2], bB[4];
    aload(aA, 0); bload(bA, 0);
    #pragma unroll 1
    for (int ks = 0; ks < 16; ks += 2) {
        aload(aB, ks + 1); bload(bB, ks + 1);
        cluster(aA, bA);
        if (ks + 2 < 16) { aload(aA, ks + 2); bload(bA, ks + 2); }
        cluster(aB, bB);
    }

    #pragma unroll
    for (int nt = 0; nt < 4; ++nt) {
        const int mcol = n0 + nt * 16 + l15;
        const float bb = b2[mcol], w3 = W3[mcol];
        #pragma unroll
        for (int jt = 0; jt < 2; ++jt) {
            #pragma unroll
            for (int r = 0; r < 4; ++r) {
                const int srow = jt * 16 + qd * 4 + r;
                const float h2 = tanhf(acc[jt][nt][r] + bb);
                const float t2 = 1.f - h2 * h2;
                const float v2 = w3 * t2;
                const size_t idx = (size_t)(b0 + srow) * HID + mcol;
                g_v2[idx] = (f16)v2;
                g_c[idx] = -2.f * h2 * v2;
            }
        }
    }
}

// ---------------- fwd3: U = V2@W2^T ; s = -2 h1 t1 u ----------------
__global__ __launch_bounds__(NT)
void fwd3() {
    __shared__ f16 alds[SPB2 * HID];
    const int b0 = blockIdx.x * SPB2;
    const int tid = threadIdx.x, lane = tid & 63, wv = tid >> 6;
    const int l15 = lane & 15, qd = lane >> 4;
    {
        const int s = tid >> 4;
        f16x8* a8 = (f16x8*)alds;
        #pragma unroll
        for (int c = 0; c < 4; ++c) {
            const int kc = (tid & 15) + c * 16;
            const f16x8 v = *(const f16x8*)&g_v2[(size_t)(b0 + s) * HID + kc * 8];
            a8[s * 64 + (kc ^ (s & 7))] = v;
        }
    }
    __syncthreads();
    const int n0 = wv * 64;
    f32x4 acc[2][4];
    #pragma unroll
    for (int a = 0; a < 2; ++a)
        #pragma unroll
        for (int c = 0; c < 4; ++c) acc[a][c] = (f32x4){0.f, 0.f, 0.f, 0.f};
    const f16x8* a8 = (const f16x8*)alds;

    auto aload = [&](f16x8* AF, int kn) {
        #pragma unroll
        for (int jt = 0; jt < 2; ++jt) {
            const int row = jt * 16 + l15;
            AF[jt] = a8[row * 64 + ((kn * 4 + qd) ^ (row & 7))];
        }
    };
    auto bload = [&](f16x8* BF, int kn) {
        #pragma unroll
        for (int nt = 0; nt < 4; ++nt)
            BF[nt] = *(const f16x8*)&g_w2fragR[(size_t)((((wv * 4 + nt) * 16 + kn) * 64) + lane) * 8];
    };
    auto cluster = [&](const f16x8* AF, const f16x8* BF) {
        #pragma unroll
        for (int jt = 0; jt < 2; ++jt)
            #pragma unroll
            for (int nt = 0; nt < 4; ++nt)
                acc[jt][nt] = __builtin_amdgcn_mfma_f32_16x16x32_f16(AF[jt], BF[nt], acc[jt][nt], 0, 0, 0);
    };

    f16x8 aA[2], bA[4], aB[2], bB[4];
    aload(aA, 0); bload(bA, 0);
    #pragma unroll 1
    for (int ms = 0; ms < 16; ms += 2) {
        aload(aB, ms + 1); bload(bB, ms + 1);
        cluster(aA, bA);
        if (ms + 2 < 16) { aload(aA, ms + 2); bload(bA, ms + 2); }
        cluster(aB, bB);
    }

    #pragma unroll
    for (int nt = 0; nt < 4; ++nt) {
        const int kcol = n0 + nt * 16 + l15;
        #pragma unroll
        for (int jt = 0; jt < 2; ++jt) {
            #pragma unroll
            for (int r = 0; r < 4; ++r) {
                const int srow = jt * 16 + qd * 4 + r;
                const size_t idx = (size_t)(b0 + srow) * HID + kcol;
                g_s[idx] = g_n2h1t1[idx] * acc[jt][nt][r];
            }
        }
    }
}

// ---------------- main: per-sample E-GEMM -> F -> R-GEMM -> fold ----------------
__global__ __launch_bounds__(NT, 2)   // cap 256 VGPR: no spill
void hnn_main(const float* __restrict__ W1, float* __restrict__ out) {
    __shared__ f16 awF[NQ * HID];          // 64KB: aw (=W1_x * t1), then F (=E*c)
    __shared__ float t1s[HID], cs[HID], ss[HID];
    __shared__ float red[NQ][2];

    const int tid = threadIdx.x, lane = tid & 63, wv = tid >> 6;
    const int l15 = lane & 15, qd = lane >> 4;
    const int b = blockIdx.x;

    if (tid < 2 * NQ) ((float*)red)[tid] = 0.f;
    t1s[tid] = g_t1[(size_t)b * HID + tid];
    cs[tid]  = g_c[(size_t)b * HID + tid];
    ss[tid]  = g_s[(size_t)b * HID + tid];

    // build aw[j][k] = W1[x_j,k] * t1[k] in f16 — COALESCED: wave owns rows
    // [wv*8, wv*8+8), lane owns cols [lane*8, lane*8+8). 1KB bursts from L2.
    {
        const int col0 = lane * 8;
        const float4 ta = *(const float4*)&g_t1[(size_t)b * HID + col0];
        const float4 tb = *(const float4*)&g_t1[(size_t)b * HID + col0 + 4];
        f16x8* aw8 = (f16x8*)awF;
        #pragma unroll
        for (int jr = 0; jr < 8; ++jr) {
            const int j = wv * 8 + jr;
            const float4 wa = *(const float4*)&W1[(size_t)j * HID + col0];
            const float4 wb = *(const float4*)&W1[(size_t)j * HID + col0 + 4];
            f16x8 h;
            h[0] = (f16)(wa.x * ta.x); h[1] = (f16)(wa.y * ta.y);
            h[2] = (f16)(wa.z * ta.z); h[3] = (f16)(wa.w * ta.w);
            h[4] = (f16)(wb.x * tb.x); h[5] = (f16)(wb.y * tb.y);
            h[6] = (f16)(wb.z * tb.z); h[7] = (f16)(wb.w * tb.w);
            aw8[j * 64 + (lane ^ (j & 7))] = h;   // permutation within row: conflict-free
        }
    }
    __syncthreads();

    const int n0 = wv * 64;
    f32x4 acc4[4][4];
    #pragma unroll
    for (int a = 0; a < 4; ++a)
        #pragma unroll
        for (int c = 0; c < 4; ++c) acc4[a][c] = (f32x4){0.f, 0.f, 0.f, 0.f};
    const f16x8* awF8 = (const f16x8*)awF;

    auto aload = [&](f16x8* AF, int kn) {
        #pragma unroll
        for (int jt = 0; jt < 4; ++jt) {
            const int row = jt * 16 + l15;
            AF[jt] = awF8[row * 64 + ((kn * 4 + qd) ^ (row & 7))];
        }
    };
    auto bloadT = [&](f16x8* BF, int kn) {
        #pragma unroll
        for (int nt = 0; nt < 4; ++nt)
            BF[nt] = *(const f16x8*)&g_w2fragT[(size_t)((((wv * 4 + nt) * 16 + kn) * 64) + lane) * 8];
    };
    auto bloadR = [&](f16x8* BF, int kn) {
        #pragma unroll
        for (int nt = 0; nt < 4; ++nt)
            BF[nt] = *(const f16x8*)&g_w2fragR[(size_t)((((wv * 4 + nt) * 16 + kn) * 64) + lane) * 8];
    };
    auto cluster = [&](const f16x8* AF, const f16x8* BF) {
        #pragma unroll
        for (int jt = 0; jt < 4; ++jt)
            #pragma unroll
            for (int nt = 0; nt < 4; ++nt)
                acc4[jt][nt] = __builtin_amdgcn_mfma_f32_16x16x32_f16(AF[jt], BF[nt], acc4[jt][nt], 0, 0, 0);
    };

    // ---- E GEMM: E[64 j][512 m] = aw @ W2 — 2-stage software pipeline ----
    {
        f16x8 aA[4], bA[4], aB[4], bB[4];
        aload(aA, 0); bloadT(bA, 0);
        #pragma unroll 1
        for (int ks = 0; ks < 16; ks += 2) {
            aload(aB, ks + 1); bloadT(bB, ks + 1);
            cluster(aA, bA);
            if (ks + 2 < 16) { aload(aA, ks + 2); bloadT(bA, ks + 2); }
            cluster(aB, bB);
        }
    }
    __syncthreads();

    // F[j][m] = E[j][m] * c[m] back into awF (swizzled)
    #pragma unroll
    for (int nt = 0; nt < 4; ++nt) {
        const int m = n0 + nt * 16 + l15;
        const float cm = cs[m];
        #pragma unroll
        for (int jt = 0; jt < 4; ++jt) {
            const int rowbase = jt * 16 + qd * 4;
            #pragma unroll
            for (int r = 0; r < 4; ++r) {
                const int j = rowbase + r;
                awF[j * HID + (((m >> 3) ^ (j & 7)) << 3) + (m & 7)] = (f16)(acc4[jt][nt][r] * cm);
            }
        }
    }
    __syncthreads();

    // ---- R GEMM: R[64 j][512 k] = F @ W2^T — 2-stage software pipeline ----
    #pragma unroll
    for (int a = 0; a < 4; ++a)
        #pragma unroll
        for (int c = 0; c < 4; ++c) acc4[a][c] = (f32x4){0.f, 0.f, 0.f, 0.f};
    {
        f16x8 aA[4], bA[4], aB[4], bB[4];
        aload(aA, 0); bloadR(bA, 0);
        #pragma unroll 1
        for (int ms = 0; ms < 16; ms += 2) {
            aload(aB, ms + 1); bloadR(bB, ms + 1);
            cluster(aA, bA);
            if (ms + 2 < 16) { aload(aA, ms + 2); bloadR(bA, ms + 2); }
            cluster(aB, bB);
        }
    }

    // fold: base = R*t1 + s*W1x ; vq = sum W1q*base ; vp = sum W1p*base
    float t1k[4], sk[4];
    #pragma unroll
    for (int nt = 0; nt < 4; ++nt) {
        const int k = n0 + nt * 16 + l15;
        t1k[nt] = t1s[k];
        sk[nt]  = ss[k];
    }
    #pragma unroll
    for (int jt = 0; jt < 4; ++jt) {
        #pragma unroll
        for (int r = 0; r < 4; ++r) {
            const int j = jt * 16 + qd * 4 + r;
            float vq = 0.f, vp = 0.f;
            #pragma unroll
            for (int nt = 0; nt < 4; ++nt) {
                const int k = n0 + nt * 16 + l15;
                const float w1x = W1[(size_t)j * HID + k];
                const float w1q = W1[(size_t)(NQ + j) * HID + k];
                const float w1p = W1[(size_t)(2 * NQ + j) * HID + k];
                const float base = acc4[jt][nt][r] * t1k[nt] + sk[nt] * w1x;
                vq += w1q * base;
                vp += w1p * base;
            }
            vq += __shfl_xor(vq, 1, 64); vq += __shfl_xor(vq, 2, 64);
            vq += __shfl_xor(vq, 4, 64); vq += __shfl_xor(vq, 8, 64);
            vp += __shfl_xor(vp, 1, 64); vp += __shfl_xor(vp, 2, 64);
            vp += __shfl_xor(vp, 4, 64); vp += __shfl_xor(vp, 8, 64);
            if (l15 == 0) {
                atomicAdd(&red[j][0], vq);
                atomicAdd(&red[j][1], vp);
            }
        }
    }
    __syncthreads();

    if (tid < NQ) {
        out[(size_t)BATCH * NQ + (size_t)b * NQ + tid] = -red[tid][0];   // p_dot = -dH_dq_dx
    } else if (tid < 2 * NQ) {
        out[(size_t)b * NQ + (tid - NQ)] = -red[tid - NQ][1];            // q_dot = -dH_dp_dx
    }
}

extern "C" void kernel_launch(void* const* d_in, const int* in_sizes, int n_in,
                              void* d_out, int out_size, void* d_ws, size_t ws_size,
                              hipStream_t stream) {
    const float* x  = (const float*)d_in[0];
    const float* q  = (const float*)d_in[1];
    const float* p  = (const float*)d_in[2];
    const float* W1 = (const float*)d_in[3];
    const float* b1 = (const float*)d_in[4];
    const float* W2 = (const float*)d_in[5];
    const float* b2 = (const float*)d_in[6];
    const float* W3 = (const float*)d_in[7];
    float* out = (float*)d_out;

    prep_frag<<<HID, HID, 0, stream>>>(W2);
    fwd1<<<BATCH / SPB1, NT, 0, stream>>>(x, q, p, W1, b1);
    fwd2<<<BATCH / SPB2, NT, 0, stream>>>(b2, W3);
    fwd3<<<BATCH / SPB2, NT, 0, stream>>>();
    hnn_main<<<BATCH, NT, 0, stream>>>(W1, out);
}

// Round 6
// 658.966 us; speedup vs baseline: 24.5029x; 1.1819x over previous
//
#include <hip/hip_runtime.h>

#define BATCH 8192
#define NQ 64          // spatial dim n
#define HID 512
#define DIN 192        // 3*n
#define NT 512         // threads per block (8 waves)
#define SPB1 16        // samples per block, fwd1
#define SPB2 32        // samples per block, fwd2/fwd3
#define SPB 2          // samples per block, main

typedef _Float16 f16;
typedef _Float16 f16x8 __attribute__((ext_vector_type(8)));
typedef float f32x4 __attribute__((ext_vector_type(4)));

// W2 in MFMA-fragment-major order (pre-swizzled global, coalesced 1KB frag loads)
__device__ f16 g_w2fragT[HID * HID];  // B-frag for C=A@W2   (cols m, contraction k)
__device__ f16 g_w2fragR[HID * HID];  // B-frag for C=A@W2^T (cols k, contraction m)
// per-sample forward intermediates
__device__ f16   g_h1[(size_t)BATCH * HID];
__device__ f16   g_v2[(size_t)BATCH * HID];
__device__ float g_t1[(size_t)BATCH * HID];
__device__ float g_n2h1t1[(size_t)BATCH * HID];
__device__ float g_c[(size_t)BATCH * HID];
__device__ float g_s[(size_t)BATCH * HID];

// ---------------- prep: fragment-major f16 W2 layouts ----------------
__global__ void prep_frag(const float* __restrict__ W2) {
    const int k = blockIdx.x;    // 512
    const int m = threadIdx.x;   // 512
    const f16 v = (f16)W2[k * HID + m];
    g_w2fragT[(size_t)((((m >> 4) * 16 + (k >> 5)) * 64) + ((m & 15) | (((k >> 3) & 3) << 4))) * 8 + (k & 7)] = v;
    g_w2fragR[(size_t)((((k >> 4) * 16 + (m >> 5)) * 64) + ((k & 15) | (((m >> 3) & 3) << 4))) * 8 + (m & 7)] = v;
}

// ---------------- fwd1: layer1 in fp32, batched over samples ----------------
__global__ __launch_bounds__(NT)
void fwd1(const float* __restrict__ x, const float* __restrict__ q,
          const float* __restrict__ p, const float* __restrict__ W1,
          const float* __restrict__ b1) {
    __shared__ float zs[SPB1][DIN];
    const int b0 = blockIdx.x * SPB1;
    const int tid = threadIdx.x;
    for (int i = tid; i < SPB1 * DIN; i += NT) {
        const int s = i / DIN, kk = i % DIN;
        float v;
        if (kk < NQ)          v = x[(b0 + s) * NQ + kk];
        else if (kk < 2 * NQ) v = q[(b0 + s) * NQ + kk - NQ];
        else                  v = p[(b0 + s) * NQ + kk - 2 * NQ];
        zs[s][kk] = v;
    }
    __syncthreads();
    const int m = tid;
    float acc[SPB1];
    #pragma unroll
    for (int s = 0; s < SPB1; ++s) acc[s] = 0.f;
    #pragma unroll 2
    for (int k = 0; k < DIN; ++k) {
        const float w = W1[k * HID + m];
        #pragma unroll
        for (int s = 0; s < SPB1; ++s) acc[s] += zs[s][k] * w;
    }
    const float bb = b1[m];
    #pragma unroll
    for (int s = 0; s < SPB1; ++s) {
        const float h1 = tanhf(acc[s] + bb);
        const float t1 = 1.f - h1 * h1;
        const size_t idx = (size_t)(b0 + s) * HID + m;
        g_h1[idx] = (f16)h1;
        g_t1[idx] = t1;
        g_n2h1t1[idx] = -2.f * h1 * t1;
    }
}

// ---------------- fwd2: H2 = tanh(H1@W2+b2) -> v2, c (32-sample MFMA tile) ----------------
__global__ __launch_bounds__(NT)
void fwd2(const float* __restrict__ b2, const float* __restrict__ W3) {
    __shared__ f16 alds[SPB2 * HID];
    const int b0 = blockIdx.x * SPB2;
    const int tid = threadIdx.x, lane = tid & 63, wv = tid >> 6;
    const int l15 = lane & 15, qd = lane >> 4;
    {
        const int s = tid >> 4;
        f16x8* a8 = (f16x8*)alds;
        #pragma unroll
        for (int c = 0; c < 4; ++c) {
            const int kc = (tid & 15) + c * 16;
            const f16x8 v = *(const f16x8*)&g_h1[(size_t)(b0 + s) * HID + kc * 8];
            a8[s * 64 + (kc ^ (s & 7))] = v;
        }
    }
    __syncthreads();
    const int n0 = wv * 64;
    f32x4 acc[2][4];
    #pragma unroll
    for (int a = 0; a < 2; ++a)
        #pragma unroll
        for (int c = 0; c < 4; ++c) acc[a][c] = (f32x4){0.f, 0.f, 0.f, 0.f};
    const f16x8* a8 = (const f16x8*)alds;

    auto aload = [&](f16x8* AF, int kn) {
        #pragma unroll
        for (int jt = 0; jt < 2; ++jt) {
            const int row = jt * 16 + l15;
            AF[jt] = a8[row * 64 + ((kn * 4 + qd) ^ (row & 7))];
        }
    };
    auto bload = [&](f16x8* BF, int kn) {
        #pragma unroll
        for (int nt = 0; nt < 4; ++nt)
            BF[nt] = *(const f16x8*)&g_w2fragT[(size_t)((((wv * 4 + nt) * 16 + kn) * 64) + lane) * 8];
    };
    auto cluster = [&](const f16x8* AF, const f16x8* BF) {
        #pragma unroll
        for (int jt = 0; jt < 2; ++jt)
            #pragma unroll
            for (int nt = 0; nt < 4; ++nt)
                acc[jt][nt] = __builtin_amdgcn_mfma_f32_16x16x32_f16(AF[jt], BF[nt], acc[jt][nt], 0, 0, 0);
    };

    f16x8 aA[2], bA[4], aB[2], bB[4];
    aload(aA, 0); bload(bA, 0);
    #pragma unroll 1
    for (int ks = 0; ks < 16; ks += 2) {
        aload(aB, ks + 1); bload(bB, ks + 1);
        cluster(aA, bA);
        if (ks + 2 < 16) { aload(aA, ks + 2); bload(bA, ks + 2); }
        cluster(aB, bB);
    }

    #pragma unroll
    for (int nt = 0; nt < 4; ++nt) {
        const int mcol = n0 + nt * 16 + l15;
        const float bb = b2[mcol], w3 = W3[mcol];
        #pragma unroll
        for (int jt = 0; jt < 2; ++jt) {
            #pragma unroll
            for (int r = 0; r < 4; ++r) {
                const int srow = jt * 16 + qd * 4 + r;
                const float h2 = tanhf(acc[jt][nt][r] + bb);
                const float t2 = 1.f - h2 * h2;
                const float v2 = w3 * t2;
                const size_t idx = (size_t)(b0 + srow) * HID + mcol;
                g_v2[idx] = (f16)v2;
                g_c[idx] = -2.f * h2 * v2;
            }
        }
    }
}

// ---------------- fwd3: U = V2@W2^T ; s = -2 h1 t1 u ----------------
__global__ __launch_bounds__(NT)
void fwd3() {
    __shared__ f16 alds[SPB2 * HID];
    const int b0 = blockIdx.x * SPB2;
    const int tid = threadIdx.x, lane = tid & 63, wv = tid >> 6;
    const int l15 = lane & 15, qd = lane >> 4;
    {
        const int s = tid >> 4;
        f16x8* a8 = (f16x8*)alds;
        #pragma unroll
        for (int c = 0; c < 4; ++c) {
            const int kc = (tid & 15) + c * 16;
            const f16x8 v = *(const f16x8*)&g_v2[(size_t)(b0 + s) * HID + kc * 8];
            a8[s * 64 + (kc ^ (s & 7))] = v;
        }
    }
    __syncthreads();
    const int n0 = wv * 64;
    f32x4 acc[2][4];
    #pragma unroll
    for (int a = 0; a < 2; ++a)
        #pragma unroll
        for (int c = 0; c < 4; ++c) acc[a][c] = (f32x4){0.f, 0.f, 0.f, 0.f};
    const f16x8* a8 = (const f16x8*)alds;

    auto aload = [&](f16x8* AF, int kn) {
        #pragma unroll
        for (int jt = 0; jt < 2; ++jt) {
            const int row = jt * 16 + l15;
            AF[jt] = a8[row * 64 + ((kn * 4 + qd) ^ (row & 7))];
        }
    };
    auto bload = [&](f16x8* BF, int kn) {
        #pragma unroll
        for (int nt = 0; nt < 4; ++nt)
            BF[nt] = *(const f16x8*)&g_w2fragR[(size_t)((((wv * 4 + nt) * 16 + kn) * 64) + lane) * 8];
    };
    auto cluster = [&](const f16x8* AF, const f16x8* BF) {
        #pragma unroll
        for (int jt = 0; jt < 2; ++jt)
            #pragma unroll
            for (int nt = 0; nt < 4; ++nt)
                acc[jt][nt] = __builtin_amdgcn_mfma_f32_16x16x32_f16(AF[jt], BF[nt], acc[jt][nt], 0, 0, 0);
    };

    f16x8 aA[2], bA[4], aB[2], bB[4];
    aload(aA, 0); bload(bA, 0);
    #pragma unroll 1
    for (int ms = 0; ms < 16; ms += 2) {
        aload(aB, ms + 1); bload(bB, ms + 1);
        cluster(aA, bA);
        if (ms + 2 < 16) { aload(aA, ms + 2); bload(bA, ms + 2); }
        cluster(aB, bB);
    }

    #pragma unroll
    for (int nt = 0; nt < 4; ++nt) {
        const int kcol = n0 + nt * 16 + l15;
        #pragma unroll
        for (int jt = 0; jt < 2; ++jt) {
            #pragma unroll
            for (int r = 0; r < 4; ++r) {
                const int srow = jt * 16 + qd * 4 + r;
                const size_t idx = (size_t)(b0 + srow) * HID + kcol;
                g_s[idx] = g_n2h1t1[idx] * acc[jt][nt][r];
            }
        }
    }
}

// ---------------- main: 2 samples/block, E-GEMM -> F -> R-GEMM -> fold ----------------
__global__ __launch_bounds__(NT, 2)   // cap 256 regs: 8 waves must fit (no spill)
void hnn_main(const float* __restrict__ W1, float* __restrict__ out) {
    __shared__ f16 awF[SPB][NQ * HID];       // 128KB: aw (=W1_x*t1), then F (=E*c)
    __shared__ float t1s[SPB][HID], cs[SPB][HID], ss[SPB][HID];
    __shared__ float red[SPB][NQ][2];

    const int tid = threadIdx.x, lane = tid & 63, wv = tid >> 6;
    const int l15 = lane & 15, qd = lane >> 4;
    const int b0 = blockIdx.x * SPB;

    if (tid < SPB * NQ * 2) ((float*)red)[tid] = 0.f;
    #pragma unroll
    for (int s = 0; s < SPB; ++s) {
        t1s[s][tid] = g_t1[(size_t)(b0 + s) * HID + tid];
        cs[s][tid]  = g_c[(size_t)(b0 + s) * HID + tid];
        ss[s][tid]  = g_s[(size_t)(b0 + s) * HID + tid];
    }

    // build aw[s][j][k] = W1[x_j,k] * t1[s][k] — coalesced; W1 row read once for both samples
    {
        const int col0 = lane * 8;
        const float4 ta0 = *(const float4*)&g_t1[(size_t)(b0 + 0) * HID + col0];
        const float4 tb0 = *(const float4*)&g_t1[(size_t)(b0 + 0) * HID + col0 + 4];
        const float4 ta1 = *(const float4*)&g_t1[(size_t)(b0 + 1) * HID + col0];
        const float4 tb1 = *(const float4*)&g_t1[(size_t)(b0 + 1) * HID + col0 + 4];
        f16x8* aw80 = (f16x8*)awF[0];
        f16x8* aw81 = (f16x8*)awF[1];
        #pragma unroll
        for (int jr = 0; jr < 8; ++jr) {
            const int j = wv * 8 + jr;
            const float4 wa = *(const float4*)&W1[(size_t)j * HID + col0];
            const float4 wb = *(const float4*)&W1[(size_t)j * HID + col0 + 4];
            f16x8 h0, h1v;
            h0[0] = (f16)(wa.x * ta0.x); h0[1] = (f16)(wa.y * ta0.y);
            h0[2] = (f16)(wa.z * ta0.z); h0[3] = (f16)(wa.w * ta0.w);
            h0[4] = (f16)(wb.x * tb0.x); h0[5] = (f16)(wb.y * tb0.y);
            h0[6] = (f16)(wb.z * tb0.z); h0[7] = (f16)(wb.w * tb0.w);
            h1v[0] = (f16)(wa.x * ta1.x); h1v[1] = (f16)(wa.y * ta1.y);
            h1v[2] = (f16)(wa.z * ta1.z); h1v[3] = (f16)(wa.w * ta1.w);
            h1v[4] = (f16)(wb.x * tb1.x); h1v[5] = (f16)(wb.y * tb1.y);
            h1v[6] = (f16)(wb.z * tb1.z); h1v[7] = (f16)(wb.w * tb1.w);
            aw80[j * 64 + (lane ^ (j & 7))] = h0;
            aw81[j * 64 + (lane ^ (j & 7))] = h1v;
        }
    }
    __syncthreads();

    const int n0 = wv * 64;
    f32x4 acc4[SPB][4][4];
    #pragma unroll
    for (int s = 0; s < SPB; ++s)
        #pragma unroll
        for (int a = 0; a < 4; ++a)
            #pragma unroll
            for (int c = 0; c < 4; ++c) acc4[s][a][c] = (f32x4){0.f, 0.f, 0.f, 0.f};

    auto aload = [&](f16x8* AF, int kn) {   // 8 frags: both samples
        #pragma unroll
        for (int s = 0; s < SPB; ++s) {
            const f16x8* a8 = (const f16x8*)awF[s];
            #pragma unroll
            for (int jt = 0; jt < 4; ++jt) {
                const int row = jt * 16 + l15;
                AF[s * 4 + jt] = a8[row * 64 + ((kn * 4 + qd) ^ (row & 7))];
            }
        }
    };
    auto bloadT = [&](f16x8* BF, int kn) {
        #pragma unroll
        for (int nt = 0; nt < 4; ++nt)
            BF[nt] = *(const f16x8*)&g_w2fragT[(size_t)((((wv * 4 + nt) * 16 + kn) * 64) + lane) * 8];
    };
    auto bloadR = [&](f16x8* BF, int kn) {
        #pragma unroll
        for (int nt = 0; nt < 4; ++nt)
            BF[nt] = *(const f16x8*)&g_w2fragR[(size_t)((((wv * 4 + nt) * 16 + kn) * 64) + lane) * 8];
    };
    auto cluster = [&](const f16x8* AF, const f16x8* BF) {  // 32 MFMA
        #pragma unroll
        for (int s = 0; s < SPB; ++s)
            #pragma unroll
            for (int jt = 0; jt < 4; ++jt)
                #pragma unroll
                for (int nt = 0; nt < 4; ++nt)
                    acc4[s][jt][nt] = __builtin_amdgcn_mfma_f32_16x16x32_f16(AF[s * 4 + jt], BF[nt], acc4[s][jt][nt], 0, 0, 0);
    };

    // ---- E GEMM: E[s][64 j][512 m] = aw @ W2 — B double-buffered, A reloaded ----
    {
        f16x8 aF[8], bA[4], bB[4];
        bloadT(bA, 0);
        #pragma unroll 1
        for (int ks = 0; ks < 16; ks += 2) {
            aload(aF, ks);
            bloadT(bB, ks + 1);
            cluster(aF, bA);
            aload(aF, ks + 1);
            if (ks + 2 < 16) bloadT(bA, ks + 2);
            cluster(aF, bB);
        }
    }
    __syncthreads();

    // F[s][j][m] = E[s][j][m] * c[s][m] back into awF (swizzled)
    #pragma unroll
    for (int s = 0; s < SPB; ++s) {
        #pragma unroll
        for (int nt = 0; nt < 4; ++nt) {
            const int m = n0 + nt * 16 + l15;
            const float cm = cs[s][m];
            #pragma unroll
            for (int jt = 0; jt < 4; ++jt) {
                const int rowbase = jt * 16 + qd * 4;
                #pragma unroll
                for (int r = 0; r < 4; ++r) {
                    const int j = rowbase + r;
                    awF[s][j * HID + (((m >> 3) ^ (j & 7)) << 3) + (m & 7)] = (f16)(acc4[s][jt][nt][r] * cm);
                }
            }
        }
    }
    __syncthreads();

    // ---- R GEMM: R[s][64 j][512 k] = F @ W2^T ----
    #pragma unroll
    for (int s = 0; s < SPB; ++s)
        #pragma unroll
        for (int a = 0; a < 4; ++a)
            #pragma unroll
            for (int c = 0; c < 4; ++c) acc4[s][a][c] = (f32x4){0.f, 0.f, 0.f, 0.f};
    {
        f16x8 aF[8], bA[4], bB[4];
        bloadR(bA, 0);
        #pragma unroll 1
        for (int ms = 0; ms < 16; ms += 2) {
            aload(aF, ms);
            bloadR(bB, ms + 1);
            cluster(aF, bA);
            aload(aF, ms + 1);
            if (ms + 2 < 16) bloadR(bA, ms + 2);
            cluster(aF, bB);
        }
    }

    // fold: base = R*t1 + s*W1x ; W1 rows loaded once, used for both samples
    float t1k[SPB][4], sk[SPB][4];
    #pragma unroll
    for (int s = 0; s < SPB; ++s)
        #pragma unroll
        for (int nt = 0; nt < 4; ++nt) {
            const int k = n0 + nt * 16 + l15;
            t1k[s][nt] = t1s[s][k];
            sk[s][nt]  = ss[s][k];
        }
    #pragma unroll
    for (int jt = 0; jt < 4; ++jt) {
        #pragma unroll
        for (int r = 0; r < 4; ++r) {
            const int j = jt * 16 + qd * 4 + r;
            float vq0 = 0.f, vp0 = 0.f, vq1 = 0.f, vp1 = 0.f;
            #pragma unroll
            for (int nt = 0; nt < 4; ++nt) {
                const int k = n0 + nt * 16 + l15;
                const float w1x = W1[(size_t)j * HID + k];
                const float w1q = W1[(size_t)(NQ + j) * HID + k];
                const float w1p = W1[(size_t)(2 * NQ + j) * HID + k];
                const float base0 = acc4[0][jt][nt][r] * t1k[0][nt] + sk[0][nt] * w1x;
                const float base1 = acc4[1][jt][nt][r] * t1k[1][nt] + sk[1][nt] * w1x;
                vq0 += w1q * base0; vp0 += w1p * base0;
                vq1 += w1q * base1; vp1 += w1p * base1;
            }
            vq0 += __shfl_xor(vq0, 1, 64); vq0 += __shfl_xor(vq0, 2, 64);
            vq0 += __shfl_xor(vq0, 4, 64); vq0 += __shfl_xor(vq0, 8, 64);
            vp0 += __shfl_xor(vp0, 1, 64); vp0 += __shfl_xor(vp0, 2, 64);
            vp0 += __shfl_xor(vp0, 4, 64); vp0 += __shfl_xor(vp0, 8, 64);
            vq1 += __shfl_xor(vq1, 1, 64); vq1 += __shfl_xor(vq1, 2, 64);
            vq1 += __shfl_xor(vq1, 4, 64); vq1 += __shfl_xor(vq1, 8, 64);
            vp1 += __shfl_xor(vp1, 1, 64); vp1 += __shfl_xor(vp1, 2, 64);
            vp1 += __shfl_xor(vp1, 4, 64); vp1 += __shfl_xor(vp1, 8, 64);
            if (l15 == 0) {
                atomicAdd(&red[0][j][0], vq0);
                atomicAdd(&red[0][j][1], vp0);
                atomicAdd(&red[1][j][0], vq1);
                atomicAdd(&red[1][j][1], vp1);
            }
        }
    }
    __syncthreads();

    if (tid < NQ) {
        out[(size_t)BATCH * NQ + (size_t)b0 * NQ + tid] = -red[0][tid][0];
        out[(size_t)b0 * NQ + tid]                      = -red[0][tid][1];
    } else if (tid < 2 * NQ) {
        const int j = tid - NQ;
        out[(size_t)BATCH * NQ + (size_t)(b0 + 1) * NQ + j] = -red[1][j][0];
        out[(size_t)(b0 + 1) * NQ + j]                      = -red[1][j][1];
    }
}

extern "C" void kernel_launch(void* const* d_in, const int* in_sizes, int n_in,
                              void* d_out, int out_size, void* d_ws, size_t ws_size,
                              hipStream_t stream) {
    const float* x  = (const float*)d_in[0];
    const float* q  = (const float*)d_in[1];
    const float* p  = (const float*)d_in[2];
    const float* W1 = (const float*)d_in[3];
    const float* b1 = (const float*)d_in[4];
    const float* W2 = (const float*)d_in[5];
    const float* b2 = (const float*)d_in[6];
    const float* W3 = (const float*)d_in[7];
    float* out = (float*)d_out;

    prep_frag<<<HID, HID, 0, stream>>>(W2);
    fwd1<<<BATCH / SPB1, NT, 0, stream>>>(x, q, p, W1, b1);
    fwd2<<<BATCH / SPB2, NT, 0, stream>>>(b2, W3);
    fwd3<<<BATCH / SPB2, NT, 0, stream>>>();
    hnn_main<<<BATCH / SPB, NT, 0, stream>>>(W1, out);
}

// Round 7
// 654.411 us; speedup vs baseline: 24.6734x; 1.0070x over previous
//
#include <hip/hip_runtime.h>

#define BATCH 8192
#define NQ 64          // spatial dim n
#define HID 512
#define DIN 192        // 3*n
#define NT 512         // threads per block (8 waves)
#define SPB1 16        // samples per block, fwd1
#define SPB2 32        // samples per block, fwd2/fwd3
#define SPB 2          // samples per block, main

typedef _Float16 f16;
typedef _Float16 f16x8 __attribute__((ext_vector_type(8)));
typedef float f32x4 __attribute__((ext_vector_type(4)));

// W2 in MFMA-fragment-major order (pre-swizzled global, coalesced 1KB frag loads)
__device__ f16 g_w2fragT[HID * HID];  // B-frag for C=A@W2   (cols m, contraction k)
__device__ f16 g_w2fragR[HID * HID];  // B-frag for C=A@W2^T (cols k, contraction m)
// per-sample forward intermediates
__device__ f16   g_h1[(size_t)BATCH * HID];
__device__ f16   g_v2[(size_t)BATCH * HID];
__device__ float g_t1[(size_t)BATCH * HID];
__device__ float g_n2h1t1[(size_t)BATCH * HID];
__device__ float g_c[(size_t)BATCH * HID];
__device__ float g_s[(size_t)BATCH * HID];

// ---------------- prep: fragment-major f16 W2 layouts ----------------
__global__ void prep_frag(const float* __restrict__ W2) {
    const int k = blockIdx.x;    // 512
    const int m = threadIdx.x;   // 512
    const f16 v = (f16)W2[k * HID + m];
    g_w2fragT[(size_t)((((m >> 4) * 16 + (k >> 5)) * 64) + ((m & 15) | (((k >> 3) & 3) << 4))) * 8 + (k & 7)] = v;
    g_w2fragR[(size_t)((((k >> 4) * 16 + (m >> 5)) * 64) + ((k & 15) | (((m >> 3) & 3) << 4))) * 8 + (m & 7)] = v;
}

// ---------------- fwd1: layer1 in fp32, batched over samples ----------------
__global__ __launch_bounds__(NT)
void fwd1(const float* __restrict__ x, const float* __restrict__ q,
          const float* __restrict__ p, const float* __restrict__ W1,
          const float* __restrict__ b1) {
    __shared__ float zs[SPB1][DIN];
    const int b0 = blockIdx.x * SPB1;
    const int tid = threadIdx.x;
    for (int i = tid; i < SPB1 * DIN; i += NT) {
        const int s = i / DIN, kk = i % DIN;
        float v;
        if (kk < NQ)          v = x[(b0 + s) * NQ + kk];
        else if (kk < 2 * NQ) v = q[(b0 + s) * NQ + kk - NQ];
        else                  v = p[(b0 + s) * NQ + kk - 2 * NQ];
        zs[s][kk] = v;
    }
    __syncthreads();
    const int m = tid;
    float acc[SPB1];
    #pragma unroll
    for (int s = 0; s < SPB1; ++s) acc[s] = 0.f;
    #pragma unroll 2
    for (int k = 0; k < DIN; ++k) {
        const float w = W1[k * HID + m];
        #pragma unroll
        for (int s = 0; s < SPB1; ++s) acc[s] += zs[s][k] * w;
    }
    const float bb = b1[m];
    #pragma unroll
    for (int s = 0; s < SPB1; ++s) {
        const float h1 = tanhf(acc[s] + bb);
        const float t1 = 1.f - h1 * h1;
        const size_t idx = (size_t)(b0 + s) * HID + m;
        g_h1[idx] = (f16)h1;
        g_t1[idx] = t1;
        g_n2h1t1[idx] = -2.f * h1 * t1;
    }
}

// ---------------- fwd2: H2 = tanh(H1@W2+b2) -> v2, c (32-sample MFMA tile) ----------------
__global__ __launch_bounds__(NT)
void fwd2(const float* __restrict__ b2, const float* __restrict__ W3) {
    __shared__ f16 alds[SPB2 * HID];
    const int b0 = blockIdx.x * SPB2;
    const int tid = threadIdx.x, lane = tid & 63, wv = tid >> 6;
    const int l15 = lane & 15, qd = lane >> 4;
    {
        const int s = tid >> 4;
        f16x8* a8 = (f16x8*)alds;
        #pragma unroll
        for (int c = 0; c < 4; ++c) {
            const int kc = (tid & 15) + c * 16;
            const f16x8 v = *(const f16x8*)&g_h1[(size_t)(b0 + s) * HID + kc * 8];
            a8[s * 64 + (kc ^ (s & 7))] = v;
        }
    }
    __syncthreads();
    const int n0 = wv * 64;
    f32x4 acc[2][4];
    #pragma unroll
    for (int a = 0; a < 2; ++a)
        #pragma unroll
        for (int c = 0; c < 4; ++c) acc[a][c] = (f32x4){0.f, 0.f, 0.f, 0.f};
    const f16x8* a8 = (const f16x8*)alds;

    auto aload = [&](f16x8* AF, int kn) {
        #pragma unroll
        for (int jt = 0; jt < 2; ++jt) {
            const int row = jt * 16 + l15;
            AF[jt] = a8[row * 64 + ((kn * 4 + qd) ^ (row & 7))];
        }
    };
    auto bload = [&](f16x8* BF, int kn) {
        #pragma unroll
        for (int nt = 0; nt < 4; ++nt)
            BF[nt] = *(const f16x8*)&g_w2fragT[(size_t)((((wv * 4 + nt) * 16 + kn) * 64) + lane) * 8];
    };
    auto cluster = [&](const f16x8* AF, const f16x8* BF) {
        #pragma unroll
        for (int jt = 0; jt < 2; ++jt)
            #pragma unroll
            for (int nt = 0; nt < 4; ++nt)
                acc[jt][nt] = __builtin_amdgcn_mfma_f32_16x16x32_f16(AF[jt], BF[nt], acc[jt][nt], 0, 0, 0);
    };

    f16x8 aA[2], bA[4], aB[2], bB[4];
    aload(aA, 0); bload(bA, 0);
    #pragma unroll 1
    for (int ks = 0; ks < 16; ks += 2) {
        aload(aB, ks + 1); bload(bB, ks + 1);
        cluster(aA, bA);
        if (ks + 2 < 16) { aload(aA, ks + 2); bload(bA, ks + 2); }
        cluster(aB, bB);
    }

    #pragma unroll
    for (int nt = 0; nt < 4; ++nt) {
        const int mcol = n0 + nt * 16 + l15;
        const float bb = b2[mcol], w3 = W3[mcol];
        #pragma unroll
        for (int jt = 0; jt < 2; ++jt) {
            #pragma unroll
            for (int r = 0; r < 4; ++r) {
                const int srow = jt * 16 + qd * 4 + r;
                const float h2 = tanhf(acc[jt][nt][r] + bb);
                const float t2 = 1.f - h2 * h2;
                const float v2 = w3 * t2;
                const size_t idx = (size_t)(b0 + srow) * HID + mcol;
                g_v2[idx] = (f16)v2;
                g_c[idx] = -2.f * h2 * v2;
            }
        }
    }
}

// ---------------- fwd3: U = V2@W2^T ; s = -2 h1 t1 u ----------------
__global__ __launch_bounds__(NT)
void fwd3() {
    __shared__ f16 alds[SPB2 * HID];
    const int b0 = blockIdx.x * SPB2;
    const int tid = threadIdx.x, lane = tid & 63, wv = tid >> 6;
    const int l15 = lane & 15, qd = lane >> 4;
    {
        const int s = tid >> 4;
        f16x8* a8 = (f16x8*)alds;
        #pragma unroll
        for (int c = 0; c < 4; ++c) {
            const int kc = (tid & 15) + c * 16;
            const f16x8 v = *(const f16x8*)&g_v2[(size_t)(b0 + s) * HID + kc * 8];
            a8[s * 64 + (kc ^ (s & 7))] = v;
        }
    }
    __syncthreads();
    const int n0 = wv * 64;
    f32x4 acc[2][4];
    #pragma unroll
    for (int a = 0; a < 2; ++a)
        #pragma unroll
        for (int c = 0; c < 4; ++c) acc[a][c] = (f32x4){0.f, 0.f, 0.f, 0.f};
    const f16x8* a8 = (const f16x8*)alds;

    auto aload = [&](f16x8* AF, int kn) {
        #pragma unroll
        for (int jt = 0; jt < 2; ++jt) {
            const int row = jt * 16 + l15;
            AF[jt] = a8[row * 64 + ((kn * 4 + qd) ^ (row & 7))];
        }
    };
    auto bload = [&](f16x8* BF, int kn) {
        #pragma unroll
        for (int nt = 0; nt < 4; ++nt)
            BF[nt] = *(const f16x8*)&g_w2fragR[(size_t)((((wv * 4 + nt) * 16 + kn) * 64) + lane) * 8];
    };
    auto cluster = [&](const f16x8* AF, const f16x8* BF) {
        #pragma unroll
        for (int jt = 0; jt < 2; ++jt)
            #pragma unroll
            for (int nt = 0; nt < 4; ++nt)
                acc[jt][nt] = __builtin_amdgcn_mfma_f32_16x16x32_f16(AF[jt], BF[nt], acc[jt][nt], 0, 0, 0);
    };

    f16x8 aA[2], bA[4], aB[2], bB[4];
    aload(aA, 0); bload(bA, 0);
    #pragma unroll 1
    for (int ms = 0; ms < 16; ms += 2) {
        aload(aB, ms + 1); bload(bB, ms + 1);
        cluster(aA, bA);
        if (ms + 2 < 16) { aload(aA, ms + 2); bload(bA, ms + 2); }
        cluster(aB, bB);
    }

    #pragma unroll
    for (int nt = 0; nt < 4; ++nt) {
        const int kcol = n0 + nt * 16 + l15;
        #pragma unroll
        for (int jt = 0; jt < 2; ++jt) {
            #pragma unroll
            for (int r = 0; r < 4; ++r) {
                const int srow = jt * 16 + qd * 4 + r;
                const size_t idx = (size_t)(b0 + srow) * HID + kcol;
                g_s[idx] = g_n2h1t1[idx] * acc[jt][nt][r];
            }
        }
    }
}

// ---------------- main: 2 samples/block, fully pipelined E -> F -> R -> fold ----------------
__global__ __launch_bounds__(NT, 2)   // cap 256 regs total (VGPR+AGPR): no spill
void hnn_main(const float* __restrict__ W1, float* __restrict__ out) {
    __shared__ f16 awF[SPB][NQ * HID];       // 128KB: aw (=W1_x*t1), then F (=E*c)
    __shared__ float t1s[SPB][HID], cs[SPB][HID], ss[SPB][HID];
    __shared__ float red[SPB][8][NQ][2];     // per-wave partials (no atomics)

    const int tid = threadIdx.x, lane = tid & 63, wv = tid >> 6;
    const int l15 = lane & 15, qd = lane >> 4;
    const int b0 = blockIdx.x * SPB;

    #pragma unroll
    for (int s = 0; s < SPB; ++s) {
        t1s[s][tid] = g_t1[(size_t)(b0 + s) * HID + tid];
        cs[s][tid]  = g_c[(size_t)(b0 + s) * HID + tid];
        ss[s][tid]  = g_s[(size_t)(b0 + s) * HID + tid];
    }

    // build aw[s][j][k] = W1[x_j,k] * t1[s][k] — coalesced; W1 row read once for both samples
    {
        const int col0 = lane * 8;
        const float4 ta0 = *(const float4*)&g_t1[(size_t)(b0 + 0) * HID + col0];
        const float4 tb0 = *(const float4*)&g_t1[(size_t)(b0 + 0) * HID + col0 + 4];
        const float4 ta1 = *(const float4*)&g_t1[(size_t)(b0 + 1) * HID + col0];
        const float4 tb1 = *(const float4*)&g_t1[(size_t)(b0 + 1) * HID + col0 + 4];
        f16x8* aw80 = (f16x8*)awF[0];
        f16x8* aw81 = (f16x8*)awF[1];
        #pragma unroll
        for (int jr = 0; jr < 8; ++jr) {
            const int j = wv * 8 + jr;
            const float4 wa = *(const float4*)&W1[(size_t)j * HID + col0];
            const float4 wb = *(const float4*)&W1[(size_t)j * HID + col0 + 4];
            f16x8 h0, h1v;
            h0[0] = (f16)(wa.x * ta0.x); h0[1] = (f16)(wa.y * ta0.y);
            h0[2] = (f16)(wa.z * ta0.z); h0[3] = (f16)(wa.w * ta0.w);
            h0[4] = (f16)(wb.x * tb0.x); h0[5] = (f16)(wb.y * tb0.y);
            h0[6] = (f16)(wb.z * tb0.z); h0[7] = (f16)(wb.w * tb0.w);
            h1v[0] = (f16)(wa.x * ta1.x); h1v[1] = (f16)(wa.y * ta1.y);
            h1v[2] = (f16)(wa.z * ta1.z); h1v[3] = (f16)(wa.w * ta1.w);
            h1v[4] = (f16)(wb.x * tb1.x); h1v[5] = (f16)(wb.y * tb1.y);
            h1v[6] = (f16)(wb.z * tb1.z); h1v[7] = (f16)(wb.w * tb1.w);
            aw80[j * 64 + (lane ^ (j & 7))] = h0;
            aw81[j * 64 + (lane ^ (j & 7))] = h1v;
        }
    }
    __syncthreads();

    const int n0 = wv * 64;
    f32x4 acc4[SPB][4][4];
    #pragma unroll
    for (int s = 0; s < SPB; ++s)
        #pragma unroll
        for (int a = 0; a < 4; ++a)
            #pragma unroll
            for (int c = 0; c < 4; ++c) acc4[s][a][c] = (f32x4){0.f, 0.f, 0.f, 0.f};

    auto aloadS = [&](f16x8* AF, int kn, int s) {   // 4 frags, one sample
        const f16x8* a8 = (const f16x8*)awF[s];
        #pragma unroll
        for (int jt = 0; jt < 4; ++jt) {
            const int row = jt * 16 + l15;
            AF[jt] = a8[row * 64 + ((kn * 4 + qd) ^ (row & 7))];
        }
    };
    auto bloadT = [&](f16x8* BF, int kn) {
        #pragma unroll
        for (int nt = 0; nt < 4; ++nt)
            BF[nt] = *(const f16x8*)&g_w2fragT[(size_t)((((wv * 4 + nt) * 16 + kn) * 64) + lane) * 8];
    };
    auto bloadR = [&](f16x8* BF, int kn) {
        #pragma unroll
        for (int nt = 0; nt < 4; ++nt)
            BF[nt] = *(const f16x8*)&g_w2fragR[(size_t)((((wv * 4 + nt) * 16 + kn) * 64) + lane) * 8];
    };
    auto clusterS = [&](const f16x8* AF, const f16x8* BF, int s) {  // 16 MFMA
        #pragma unroll
        for (int jt = 0; jt < 4; ++jt)
            #pragma unroll
            for (int nt = 0; nt < 4; ++nt)
                acc4[s][jt][nt] = __builtin_amdgcn_mfma_f32_16x16x32_f16(AF[jt], BF[nt], acc4[s][jt][nt], 0, 0, 0);
    };

    // ---- E GEMM: E[s][64 j][512 m] = aw @ W2 ----
    // Half-step pipeline: every cluster's A loaded >=1 cluster (~310cyc) ahead,
    // B loaded ~2 clusters ahead. aP/aQ = 4-frag A buffers (32 VGPR total).
    {
        f16x8 aP[4], aQ[4], bA[4], bB[4];
        aloadS(aP, 0, 0); bloadT(bA, 0);
        #pragma unroll 1
        for (int ks = 0; ks < 16; ks += 2) {
            aloadS(aQ, ks, 1);
            bloadT(bB, ks + 1);
            clusterS(aP, bA, 0);
            aloadS(aP, ks + 1, 0);
            clusterS(aQ, bA, 1);
            aloadS(aQ, ks + 1, 1);
            if (ks + 2 < 16) bloadT(bA, ks + 2);
            clusterS(aP, bB, 0);
            if (ks + 2 < 16) aloadS(aP, ks + 2, 0);
            clusterS(aQ, bB, 1);
        }
    }
    __syncthreads();

    // F[s][j][m] = E[s][j][m] * c[s][m] back into awF (swizzled)
    #pragma unroll
    for (int s = 0; s < SPB; ++s) {
        #pragma unroll
        for (int nt = 0; nt < 4; ++nt) {
            const int m = n0 + nt * 16 + l15;
            const float cm = cs[s][m];
            #pragma unroll
            for (int jt = 0; jt < 4; ++jt) {
                const int rowbase = jt * 16 + qd * 4;
                #pragma unroll
                for (int r = 0; r < 4; ++r) {
                    const int j = rowbase + r;
                    awF[s][j * HID + (((m >> 3) ^ (j & 7)) << 3) + (m & 7)] = (f16)(acc4[s][jt][nt][r] * cm);
                }
            }
        }
    }
    __syncthreads();

    // ---- R GEMM: R[s][64 j][512 k] = F @ W2^T — same pipeline ----
    #pragma unroll
    for (int s = 0; s < SPB; ++s)
        #pragma unroll
        for (int a = 0; a < 4; ++a)
            #pragma unroll
            for (int c = 0; c < 4; ++c) acc4[s][a][c] = (f32x4){0.f, 0.f, 0.f, 0.f};
    {
        f16x8 aP[4], aQ[4], bA[4], bB[4];
        aloadS(aP, 0, 0); bloadR(bA, 0);
        #pragma unroll 1
        for (int ms = 0; ms < 16; ms += 2) {
            aloadS(aQ, ms, 1);
            bloadR(bB, ms + 1);
            clusterS(aP, bA, 0);
            aloadS(aP, ms + 1, 0);
            clusterS(aQ, bA, 1);
            aloadS(aQ, ms + 1, 1);
            if (ms + 2 < 16) bloadR(bA, ms + 2);
            clusterS(aP, bB, 0);
            if (ms + 2 < 16) aloadS(aP, ms + 2, 0);
            clusterS(aQ, bB, 1);
        }
    }

    // fold: base = R*t1 + s*W1x ; W1 rows loaded once, used for both samples
    float t1k[SPB][4], sk[SPB][4];
    #pragma unroll
    for (int s = 0; s < SPB; ++s)
        #pragma unroll
        for (int nt = 0; nt < 4; ++nt) {
            const int k = n0 + nt * 16 + l15;
            t1k[s][nt] = t1s[s][k];
            sk[s][nt]  = ss[s][k];
        }
    #pragma unroll
    for (int jt = 0; jt < 4; ++jt) {
        #pragma unroll
        for (int r = 0; r < 4; ++r) {
            const int j = jt * 16 + qd * 4 + r;
            float vq0 = 0.f, vp0 = 0.f, vq1 = 0.f, vp1 = 0.f;
            #pragma unroll
            for (int nt = 0; nt < 4; ++nt) {
                const int k = n0 + nt * 16 + l15;
                const float w1x = W1[(size_t)j * HID + k];
                const float w1q = W1[(size_t)(NQ + j) * HID + k];
                const float w1p = W1[(size_t)(2 * NQ + j) * HID + k];
                const float base0 = acc4[0][jt][nt][r] * t1k[0][nt] + sk[0][nt] * w1x;
                const float base1 = acc4[1][jt][nt][r] * t1k[1][nt] + sk[1][nt] * w1x;
                vq0 += w1q * base0; vp0 += w1p * base0;
                vq1 += w1q * base1; vp1 += w1p * base1;
            }
            vq0 += __shfl_xor(vq0, 1, 64); vq0 += __shfl_xor(vq0, 2, 64);
            vq0 += __shfl_xor(vq0, 4, 64); vq0 += __shfl_xor(vq0, 8, 64);
            vp0 += __shfl_xor(vp0, 1, 64); vp0 += __shfl_xor(vp0, 2, 64);
            vp0 += __shfl_xor(vp0, 4, 64); vp0 += __shfl_xor(vp0, 8, 64);
            vq1 += __shfl_xor(vq1, 1, 64); vq1 += __shfl_xor(vq1, 2, 64);
            vq1 += __shfl_xor(vq1, 4, 64); vq1 += __shfl_xor(vq1, 8, 64);
            vp1 += __shfl_xor(vp1, 1, 64); vp1 += __shfl_xor(vp1, 2, 64);
            vp1 += __shfl_xor(vp1, 4, 64); vp1 += __shfl_xor(vp1, 8, 64);
            if (l15 == 0) {
                red[0][wv][j][0] = vq0;
                red[0][wv][j][1] = vp0;
                red[1][wv][j][0] = vq1;
                red[1][wv][j][1] = vp1;
            }
        }
    }
    __syncthreads();

    if (tid < SPB * NQ * 2) {
        const int s = tid >> 7, j = (tid >> 1) & 63, c = tid & 1;
        float v = 0.f;
        #pragma unroll
        for (int w = 0; w < 8; ++w) v += red[s][w][j][c];
        if (c == 0) out[(size_t)BATCH * NQ + (size_t)(b0 + s) * NQ + j] = -v;  // p_dot = -dH_dq_dx
        else        out[(size_t)(b0 + s) * NQ + j] = -v;                       // q_dot = -dH_dp_dx
    }
}

extern "C" void kernel_launch(void* const* d_in, const int* in_sizes, int n_in,
                              void* d_out, int out_size, void* d_ws, size_t ws_size,
                              hipStream_t stream) {
    const float* x  = (const float*)d_in[0];
    const float* q  = (const float*)d_in[1];
    const float* p  = (const float*)d_in[2];
    const float* W1 = (const float*)d_in[3];
    const float* b1 = (const float*)d_in[4];
    const float* W2 = (const float*)d_in[5];
    const float* b2 = (const float*)d_in[6];
    const float* W3 = (const float*)d_in[7];
    float* out = (float*)d_out;

    prep_frag<<<HID, HID, 0, stream>>>(W2);
    fwd1<<<BATCH / SPB1, NT, 0, stream>>>(x, q, p, W1, b1);
    fwd2<<<BATCH / SPB2, NT, 0, stream>>>(b2, W3);
    fwd3<<<BATCH / SPB2, NT, 0, stream>>>();
    hnn_main<<<BATCH / SPB, NT, 0, stream>>>(W1, out);
}